// Round 1
// baseline (257.510 us; speedup 1.0000x reference)
//
#include <hip/hip_runtime.h>
#include <stdint.h>
#include <stddef.h>

#define EMB 768
#define SEQ 4096
#define NH 12
#define DH 64

typedef __attribute__((ext_vector_type(8))) short short8;
typedef __attribute__((ext_vector_type(4))) float f32x4;

// ---------- helpers ----------
static __device__ __forceinline__ unsigned short f2bf(float f) {
  union { float f; uint32_t u; } v; v.f = f;
  uint32_t u = v.u;
  uint32_t r = (u + 0x7FFFu + ((u >> 16) & 1u)) >> 16;
  return (unsigned short)r;
}

static __device__ __forceinline__ void gl_lds16(const void* g, void* l) {
  __builtin_amdgcn_global_load_lds(
      (const __attribute__((address_space(1))) uint32_t*)g,
      (__attribute__((address_space(3))) uint32_t*)l, 16, 0, 0);
}

// ---------- fp32 -> bf16 convert ----------
__global__ void cvt_kernel(const float* __restrict__ in,
                           unsigned short* __restrict__ out, int n) {
  int stride = gridDim.x * blockDim.x * 4;
  for (int i = (blockIdx.x * blockDim.x + threadIdx.x) * 4; i < n; i += stride) {
    float4 v = *reinterpret_cast<const float4*>(in + i);
    ushort4 o;
    o.x = f2bf(v.x); o.y = f2bf(v.y); o.z = f2bf(v.z); o.w = f2bf(v.w);
    *reinterpret_cast<ushort4*>(out + i) = o;
  }
}

// ---------- GEMM: C[M][N] = A[M][K] * W[N][K]^T + bias ----------
// 128x128 tile, BK=64, 4 waves (2x2), 16x16x32 bf16 MFMA.
// LDS XOR-swizzle ((row&7)<<4) applied on the *global source* address
// (global_load_lds writes linearly), undone on the ds_read side.
template <int OUT_F32>
__global__ __launch_bounds__(256, 2) void gemm_bt(
    const unsigned short* __restrict__ A, const unsigned short* __restrict__ W,
    const float* __restrict__ bias, void* __restrict__ Cout,
    int M, int N, int K) {
  __shared__ unsigned short Alds[128 * 64];
  __shared__ unsigned short Blds[128 * 64];
  const int t = threadIdx.x;
  const int lane = t & 63;
  const int wave = t >> 6;
  const int wr = wave >> 1, wc = wave & 1;
  const int bm = blockIdx.x, bn = blockIdx.y;
  const int lm = lane & 15, lg = lane >> 4;

  f32x4 acc[4][4];
#pragma unroll
  for (int i = 0; i < 4; ++i)
#pragma unroll
    for (int j = 0; j < 4; ++j) acc[i][j] = (f32x4){0.f, 0.f, 0.f, 0.f};

  const int srow = t >> 3;          // 0..31 staging row within issue
  const int scsw = (t & 7) * 16;    // linear LDS colbyte

  const int nK = K >> 6;
  for (int kt = 0; kt < nK; ++kt) {
    const int k0 = kt << 6;
#pragma unroll
    for (int i = 0; i < 4; ++i) {
      int row = i * 32 + srow;
      int cb = scsw ^ ((row & 7) << 4);
      gl_lds16(A + (size_t)(bm * 128 + row) * K + k0 + (cb >> 1),
               (char*)Alds + i * 4096 + t * 16);
      gl_lds16(W + (size_t)(bn * 128 + row) * K + k0 + (cb >> 1),
               (char*)Blds + i * 4096 + t * 16);
    }
    __syncthreads();
#pragma unroll
    for (int kk = 0; kk < 2; ++kk) {
      short8 af[4], bfr[4];
#pragma unroll
      for (int i = 0; i < 4; ++i) {
        int rowa = wr * 64 + i * 16 + lm;
        int cba = (kk * 64 + lg * 16) ^ ((rowa & 7) << 4);
        af[i] = *reinterpret_cast<const short8*>((const char*)Alds + rowa * 128 + cba);
        int rowb = wc * 64 + i * 16 + lm;
        int cbb = (kk * 64 + lg * 16) ^ ((rowb & 7) << 4);
        bfr[i] = *reinterpret_cast<const short8*>((const char*)Blds + rowb * 128 + cbb);
      }
#pragma unroll
      for (int i = 0; i < 4; ++i)
#pragma unroll
        for (int j = 0; j < 4; ++j)
          acc[i][j] = __builtin_amdgcn_mfma_f32_16x16x32_bf16(af[i], bfr[j], acc[i][j], 0, 0, 0);
    }
    __syncthreads();
  }
  // epilogue: C row = (lane>>4)*4 + reg, col = lane&15  (verified C/D layout)
#pragma unroll
  for (int i = 0; i < 4; ++i) {
    int row0 = bm * 128 + wr * 64 + i * 16 + lg * 4;
#pragma unroll
    for (int j = 0; j < 4; ++j) {
      int col = bn * 128 + wc * 64 + j * 16 + lm;
      float b = bias[col];
#pragma unroll
      for (int r = 0; r < 4; ++r) {
        float v = acc[i][j][r] + b;
        if (OUT_F32)
          ((float*)Cout)[(size_t)(row0 + r) * N + col] = v;
        else
          ((unsigned short*)Cout)[(size_t)(row0 + r) * N + col] = f2bf(v);
      }
    }
  }
}

// ---------- V transpose: V[SEQ][EMB] -> Vt[EMB][SEQ] (bf16) ----------
__global__ void transpose_kernel(const unsigned short* __restrict__ in,
                                 unsigned short* __restrict__ out) {
  __shared__ unsigned short tile[32][33];
  int tx = threadIdx.x, ty = threadIdx.y;   // 32 x 8
  int e0 = blockIdx.x * 32, s0 = blockIdx.y * 32;
#pragma unroll
  for (int i = 0; i < 4; ++i)
    tile[ty + i * 8][tx] = in[(size_t)(s0 + ty + i * 8) * EMB + e0 + tx];
  __syncthreads();
#pragma unroll
  for (int i = 0; i < 4; ++i)
    out[(size_t)(e0 + ty + i * 8) * SEQ + s0 + tx] = tile[tx][ty + i * 8];
}

// ---------- flash attention ----------
// grid: (SEQ/64, NH). 4 waves/block, 16 q-rows per wave, KV tile = 64.
__global__ __launch_bounds__(256, 2) void attn_kernel(
    const unsigned short* __restrict__ Q, const unsigned short* __restrict__ Kb,
    const unsigned short* __restrict__ Vt, const float* __restrict__ mask,
    unsigned short* __restrict__ Out) {
  __shared__ unsigned short Klds[64 * 64];     // [kv][d], swizzled rows (128B)
  __shared__ unsigned short Vlds[64 * 64];     // [d][kv], swizzled rows (128B)
  __shared__ unsigned short Plds[4][16 * 88];  // per-wave P, row stride 88 (176B)

  const int t = threadIdx.x;
  const int lane = t & 63;
  const int wave = t >> 6;
  const int h = blockIdx.y;
  const int q0 = blockIdx.x * 64 + wave * 16;
  const int lm = lane & 15, lg = lane >> 4;

  // Q fragments in registers: lane holds row lm, k-octet lg (A-frag layout)
  short8 qf[2];
#pragma unroll
  for (int d = 0; d < 2; ++d)
    qf[d] = *reinterpret_cast<const short8*>(
        Q + (size_t)(q0 + lm) * EMB + h * 64 + d * 32 + lg * 8);

  f32x4 oacc[4];
#pragma unroll
  for (int i = 0; i < 4; ++i) oacc[i] = (f32x4){0.f, 0.f, 0.f, 0.f};
  float mrow[4], lrow[4];
#pragma unroll
  for (int r = 0; r < 4; ++r) { mrow[r] = -1e30f; lrow[r] = 0.f; }

  const int srow = t >> 3;
  const int scsw = (t & 7) * 16;
  unsigned short* Pw = &Plds[wave][0];

  for (int kt = 0; kt < SEQ / 64; ++kt) {
    const int kv0 = kt * 64;
    // stage K tile [64][64] and Vt tile [64][64]
#pragma unroll
    for (int i = 0; i < 2; ++i) {
      int row = i * 32 + srow;
      int cb = scsw ^ ((row & 7) << 4);
      gl_lds16(Kb + (size_t)(kv0 + row) * EMB + h * 64 + (cb >> 1),
               (char*)Klds + i * 4096 + t * 16);
      gl_lds16(Vt + (size_t)(h * 64 + row) * SEQ + kv0 + (cb >> 1),
               (char*)Vlds + i * 4096 + t * 16);
    }
    __syncthreads();

    // QK^T: scores C-tile 16x64 (4 subtiles of 16 kv)
    f32x4 sc[4];
#pragma unroll
    for (int j = 0; j < 4; ++j) {
      sc[j] = (f32x4){0.f, 0.f, 0.f, 0.f};
#pragma unroll
      for (int d = 0; d < 2; ++d) {
        int kv = j * 16 + lm;
        int cb = (d * 64 + lg * 16) ^ ((kv & 7) << 4);
        short8 kf = *reinterpret_cast<const short8*>((const char*)Klds + kv * 128 + cb);
        sc[j] = __builtin_amdgcn_mfma_f32_16x16x32_bf16(qf[d], kf, sc[j], 0, 0, 0);
      }
    }
    // scale + additive mask (col = kv0 + j*16 + lm per lane)
    float mb[4];
#pragma unroll
    for (int j = 0; j < 4; ++j)
      mb[j] = -10000.f * (1.f - mask[kv0 + j * 16 + lm]);
#pragma unroll
    for (int j = 0; j < 4; ++j)
#pragma unroll
      for (int r = 0; r < 4; ++r)
        sc[j][r] = sc[j][r] * 0.125f + mb[j];

    // online softmax; row r of this lane = lg*4 + r; row-reduce = 16-lane group
    float tmax[4];
#pragma unroll
    for (int r = 0; r < 4; ++r)
      tmax[r] = fmaxf(fmaxf(sc[0][r], sc[1][r]), fmaxf(sc[2][r], sc[3][r]));
#pragma unroll
    for (int off = 1; off < 16; off <<= 1)
#pragma unroll
      for (int r = 0; r < 4; ++r)
        tmax[r] = fmaxf(tmax[r], __shfl_xor(tmax[r], off, 64));
    float sf[4], rs[4];
#pragma unroll
    for (int r = 0; r < 4; ++r) {
      float mn = fmaxf(mrow[r], tmax[r]);
      sf[r] = __expf(mrow[r] - mn);
      mrow[r] = mn;
    }
#pragma unroll
    for (int j = 0; j < 4; ++j)
#pragma unroll
      for (int r = 0; r < 4; ++r)
        sc[j][r] = __expf(sc[j][r] - mrow[r]);
#pragma unroll
    for (int r = 0; r < 4; ++r)
      rs[r] = sc[0][r] + sc[1][r] + sc[2][r] + sc[3][r];
#pragma unroll
    for (int off = 1; off < 16; off <<= 1)
#pragma unroll
      for (int r = 0; r < 4; ++r)
        rs[r] += __shfl_xor(rs[r], off, 64);
#pragma unroll
    for (int r = 0; r < 4; ++r)
      lrow[r] = lrow[r] * sf[r] + rs[r];
#pragma unroll
    for (int i = 0; i < 4; ++i)
#pragma unroll
      for (int r = 0; r < 4; ++r)
        oacc[i][r] *= sf[r];

    // P (C-layout) -> per-wave LDS [16][88] row-major
#pragma unroll
    for (int j = 0; j < 4; ++j)
#pragma unroll
      for (int r = 0; r < 4; ++r)
        Pw[(lg * 4 + r) * 88 + j * 16 + lm] = f2bf(sc[j][r]);

    // PV: A = P (row lm, kv-octet), B = V from Vt-lds (col d=lm... col=lane&15)
#pragma unroll
    for (int ks = 0; ks < 2; ++ks) {
      short8 pa = *reinterpret_cast<const short8*>(Pw + lm * 88 + ks * 32 + lg * 8);
#pragma unroll
      for (int i = 0; i < 4; ++i) {
        int drow = i * 16 + lm;
        int cb = (ks * 64 + lg * 16) ^ ((drow & 7) << 4);
        short8 vf = *reinterpret_cast<const short8*>((const char*)Vlds + drow * 128 + cb);
        oacc[i] = __builtin_amdgcn_mfma_f32_16x16x32_bf16(pa, vf, oacc[i], 0, 0, 0);
      }
    }
    __syncthreads();
  }

  // epilogue
#pragma unroll
  for (int i = 0; i < 4; ++i) {
    int col = h * 64 + i * 16 + lm;
#pragma unroll
    for (int r = 0; r < 4; ++r) {
      float v = oacc[i][r] / lrow[r];
      Out[(size_t)(q0 + lg * 4 + r) * EMB + col] = f2bf(v);
    }
  }
}

// ---------- launch ----------
extern "C" void kernel_launch(void* const* d_in, const int* in_sizes, int n_in,
                              void* d_out, int out_size, void* d_ws, size_t ws_size,
                              hipStream_t stream) {
  const float* x    = (const float*)d_in[0];
  const float* mask = (const float*)d_in[1];
  const float* Wq   = (const float*)d_in[2];
  const float* bq   = (const float*)d_in[3];
  const float* Wk   = (const float*)d_in[4];
  const float* bk   = (const float*)d_in[5];
  const float* Wv   = (const float*)d_in[6];
  const float* bv   = (const float*)d_in[7];
  const float* Wo   = (const float*)d_in[8];
  const float* bo   = (const float*)d_in[9];
  float* out = (float*)d_out;

  char* ws = (char*)d_ws;
  const size_t SZ_X = (size_t)SEQ * EMB * 2;   // 6291456
  const size_t SZ_W = (size_t)EMB * EMB * 2;   // 1179648
  unsigned short* xb  = (unsigned short*)(ws);
  unsigned short* wqb = (unsigned short*)(ws + SZ_X);
  unsigned short* wkb = (unsigned short*)(ws + SZ_X + SZ_W);
  unsigned short* wvb = (unsigned short*)(ws + SZ_X + 2 * SZ_W);
  unsigned short* wob = (unsigned short*)(ws + SZ_X + 3 * SZ_W);
  unsigned short* Qb  = (unsigned short*)(ws + SZ_X + 4 * SZ_W);
  unsigned short* Kbuf= (unsigned short*)(ws + 2 * SZ_X + 4 * SZ_W);
  unsigned short* Vb  = (unsigned short*)(ws + 3 * SZ_X + 4 * SZ_W);
  unsigned short* Vtb = (unsigned short*)(ws + 4 * SZ_X + 4 * SZ_W);
  unsigned short* Ab  = (unsigned short*)(ws + 5 * SZ_X + 4 * SZ_W);

  // converts
  cvt_kernel<<<1536, 256, 0, stream>>>(x, xb, SEQ * EMB);
  cvt_kernel<<<576, 256, 0, stream>>>(Wq, wqb, EMB * EMB);
  cvt_kernel<<<576, 256, 0, stream>>>(Wk, wkb, EMB * EMB);
  cvt_kernel<<<576, 256, 0, stream>>>(Wv, wvb, EMB * EMB);
  cvt_kernel<<<576, 256, 0, stream>>>(Wo, wob, EMB * EMB);

  // QKV projections
  dim3 g1(SEQ / 128, EMB / 128);
  gemm_bt<0><<<g1, 256, 0, stream>>>(xb, wqb, bq, Qb, SEQ, EMB, EMB);
  gemm_bt<0><<<g1, 256, 0, stream>>>(xb, wkb, bk, Kbuf, SEQ, EMB, EMB);
  gemm_bt<0><<<g1, 256, 0, stream>>>(xb, wvb, bv, Vb, SEQ, EMB, EMB);

  // V transpose
  transpose_kernel<<<dim3(EMB / 32, SEQ / 32), dim3(32, 8), 0, stream>>>(Vb, Vtb);

  // attention
  attn_kernel<<<dim3(SEQ / 64, NH), 256, 0, stream>>>(Qb, Kbuf, Vtb, mask, Ab);

  // output projection (f32 out)
  gemm_bt<1><<<g1, 256, 0, stream>>>(Ab, wob, bo, out, SEQ, EMB, EMB);
}

// Round 3
// 165.353 us; speedup vs baseline: 1.5573x; 1.5573x over previous
//
#include <hip/hip_runtime.h>
#include <stdint.h>
#include <stddef.h>

#define EMB 768
#define SEQ 4096
#define NH 12
#define DH 64
#define LOG2E 1.44269504f

typedef __attribute__((ext_vector_type(8))) short short8;
typedef __attribute__((ext_vector_type(4))) float f32x4;
typedef __attribute__((ext_vector_type(16))) float f32x16;

// ---------- helpers ----------
static __device__ __forceinline__ unsigned short f2bf(float f) {
  union { float f; uint32_t u; } v; v.f = f;
  uint32_t u = v.u;
  return (unsigned short)((u + 0x7FFFu + ((u >> 16) & 1u)) >> 16);
}

static __device__ __forceinline__ void gl_lds16(const void* g, void* l) {
  __builtin_amdgcn_global_load_lds(
      (const __attribute__((address_space(1))) uint32_t*)g,
      (__attribute__((address_space(3))) uint32_t*)l, 16, 0, 0);
}

// ---------- fp32 -> bf16 convert ----------
__global__ void cvt_kernel(const float* __restrict__ in,
                           unsigned short* __restrict__ out, int n) {
  int stride = gridDim.x * blockDim.x * 4;
  for (int i = (blockIdx.x * blockDim.x + threadIdx.x) * 4; i < n; i += stride) {
    float4 v = *reinterpret_cast<const float4*>(in + i);
    ushort4 o;
    o.x = f2bf(v.x); o.y = f2bf(v.y); o.z = f2bf(v.z); o.w = f2bf(v.w);
    *reinterpret_cast<ushort4*>(out + i) = o;
  }
}

// 4 weight matrices in one launch (blockIdx.y selects)
__global__ void cvt4_kernel(const float* __restrict__ i0, const float* __restrict__ i1,
                            const float* __restrict__ i2, const float* __restrict__ i3,
                            unsigned short* __restrict__ o0, unsigned short* __restrict__ o1,
                            unsigned short* __restrict__ o2, unsigned short* __restrict__ o3,
                            int n) {
  int y = blockIdx.y;
  const float* in = y == 0 ? i0 : y == 1 ? i1 : y == 2 ? i2 : i3;
  unsigned short* out = y == 0 ? o0 : y == 1 ? o1 : y == 2 ? o2 : o3;
  int stride = gridDim.x * blockDim.x * 4;
  for (int i = (blockIdx.x * blockDim.x + threadIdx.x) * 4; i < n; i += stride) {
    float4 v = *reinterpret_cast<const float4*>(in + i);
    ushort4 o;
    o.x = f2bf(v.x); o.y = f2bf(v.y); o.z = f2bf(v.z); o.w = f2bf(v.w);
    *reinterpret_cast<ushort4*>(out + i) = o;
  }
}

// mask -> additive bias in exp2 domain
__global__ void mbias_kernel(const float* __restrict__ mask, float* __restrict__ mb2, int n) {
  int i = blockIdx.x * blockDim.x + threadIdx.x;
  if (i < n) mb2[i] = -10000.f * (1.f - mask[i]) * LOG2E;
}

// ---------- GEMM core: C[M][N] = A[M][K] * W[N][K]^T + bias ----------
template <int OUT_F32>
static __device__ __forceinline__ void gemm128(
    const unsigned short* __restrict__ A, const unsigned short* __restrict__ W,
    const float* __restrict__ bias, void* __restrict__ Cout,
    int M, int N, int K, int bm, int bn) {
  __shared__ unsigned short Alds[128 * 64];
  __shared__ unsigned short Blds[128 * 64];
  const int t = threadIdx.x;
  const int lane = t & 63;
  const int wave = t >> 6;
  const int wr = wave >> 1, wc = wave & 1;
  const int lm = lane & 15, lg = lane >> 4;

  f32x4 acc[4][4];
#pragma unroll
  for (int i = 0; i < 4; ++i)
#pragma unroll
    for (int j = 0; j < 4; ++j) acc[i][j] = (f32x4){0.f, 0.f, 0.f, 0.f};

  const int srow = t >> 3;
  const int scsw = (t & 7) * 16;

  const int nK = K >> 6;
  for (int kt = 0; kt < nK; ++kt) {
    const int k0 = kt << 6;
#pragma unroll
    for (int i = 0; i < 4; ++i) {
      int row = i * 32 + srow;
      int cb = scsw ^ ((row & 7) << 4);
      gl_lds16(A + (size_t)(bm * 128 + row) * K + k0 + (cb >> 1),
               (char*)Alds + i * 4096 + t * 16);
      gl_lds16(W + (size_t)(bn * 128 + row) * K + k0 + (cb >> 1),
               (char*)Blds + i * 4096 + t * 16);
    }
    __syncthreads();
#pragma unroll
    for (int kk = 0; kk < 2; ++kk) {
      short8 af[4], bfr[4];
#pragma unroll
      for (int i = 0; i < 4; ++i) {
        int rowa = wr * 64 + i * 16 + lm;
        int cba = (kk * 64 + lg * 16) ^ ((rowa & 7) << 4);
        af[i] = *reinterpret_cast<const short8*>((const char*)Alds + rowa * 128 + cba);
        int rowb = wc * 64 + i * 16 + lm;
        int cbb = (kk * 64 + lg * 16) ^ ((rowb & 7) << 4);
        bfr[i] = *reinterpret_cast<const short8*>((const char*)Blds + rowb * 128 + cbb);
      }
#pragma unroll
      for (int i = 0; i < 4; ++i)
#pragma unroll
        for (int j = 0; j < 4; ++j)
          acc[i][j] = __builtin_amdgcn_mfma_f32_16x16x32_bf16(af[i], bfr[j], acc[i][j], 0, 0, 0);
    }
    __syncthreads();
  }
#pragma unroll
  for (int i = 0; i < 4; ++i) {
    int row0 = bm * 128 + wr * 64 + i * 16 + lg * 4;
#pragma unroll
    for (int j = 0; j < 4; ++j) {
      int col = bn * 128 + wc * 64 + j * 16 + lm;
      float b = bias[col];
#pragma unroll
      for (int r = 0; r < 4; ++r) {
        float v = acc[i][j][r] + b;
        if (OUT_F32)
          ((float*)Cout)[(size_t)(row0 + r) * N + col] = v;
        else
          ((unsigned short*)Cout)[(size_t)(row0 + r) * N + col] = f2bf(v);
      }
    }
  }
}

__global__ __launch_bounds__(256, 2) void gemm_wo(
    const unsigned short* __restrict__ A, const unsigned short* __restrict__ W,
    const float* __restrict__ bias, float* __restrict__ C) {
  gemm128<1>(A, W, bias, C, SEQ, EMB, EMB, blockIdx.x, blockIdx.y);
}

__global__ __launch_bounds__(256, 2) void qkv_gemm(
    const unsigned short* __restrict__ A,
    const unsigned short* __restrict__ W0, const unsigned short* __restrict__ W1,
    const unsigned short* __restrict__ W2,
    const float* __restrict__ b0, const float* __restrict__ b1, const float* __restrict__ b2,
    unsigned short* __restrict__ O0, unsigned short* __restrict__ O1,
    unsigned short* __restrict__ O2) {
  const int z = blockIdx.z;
  const unsigned short* W = z == 0 ? W0 : z == 1 ? W1 : W2;
  const float* bias = z == 0 ? b0 : z == 1 ? b1 : b2;
  unsigned short* O = z == 0 ? O0 : z == 1 ? O1 : O2;
  gemm128<0>(A, W, bias, O, SEQ, EMB, EMB, blockIdx.x, blockIdx.y);
}

// ---------- V transpose: V[SEQ][EMB] -> Vt[EMB][SEQ] (bf16) ----------
__global__ void transpose_kernel(const unsigned short* __restrict__ in,
                                 unsigned short* __restrict__ out) {
  __shared__ unsigned short tile[32][33];
  int tx = threadIdx.x, ty = threadIdx.y;   // 32 x 8
  int e0 = blockIdx.x * 32, s0 = blockIdx.y * 32;
#pragma unroll
  for (int i = 0; i < 4; ++i)
    tile[ty + i * 8][tx] = in[(size_t)(s0 + ty + i * 8) * EMB + e0 + tx];
  __syncthreads();
#pragma unroll
  for (int i = 0; i < 4; ++i)
    out[(size_t)(e0 + ty + i * 8) * SEQ + s0 + tx] = tile[tx][ty + i * 8];
}

// ---------- flash attention, swapped-QK^T 32x32 structure ----------
// grid: 768 blocks (64 q-blocks x 12 heads via bijective XCD swizzle),
// 2 waves/block, 32 q-rows/wave, KV tile = 64, double-buffered LDS.
__global__ __launch_bounds__(128, 2) void attn_kernel(
    const unsigned short* __restrict__ Q, const unsigned short* __restrict__ Kb,
    const unsigned short* __restrict__ Vt, const float* __restrict__ mb2,
    unsigned short* __restrict__ Out) {
  __shared__ unsigned short Klds[2][64 * 64];   // [kv][d], swizzled 128B rows
  __shared__ unsigned short Vlds[2][64 * 64];   // [d][kv], swizzled 128B rows
  __shared__ __align__(16) float bcs[2][32];    // per-wave broadcast scratch

  const int t = threadIdx.x;
  const int lane = t & 63;
  const int wave = t >> 6;
  const int o = blockIdx.x;
  const int wg = (o & 7) * 96 + (o >> 3);       // XCD swizzle (768 % 8 == 0)
  const int head = wg >> 6;
  const int q0 = (wg & 63) * 64 + wave * 32;
  const int lm = lane & 31;
  const int h = lane >> 5;

  // Q B-fragments (col = q = lm, k-octet = d = 16ks + 8h .. +8)
  short8 qf[4];
#pragma unroll
  for (int ks = 0; ks < 4; ++ks)
    qf[ks] = *reinterpret_cast<const short8*>(
        Q + (size_t)(q0 + lm) * EMB + head * DH + ks * 16 + h * 8);

  f32x16 oacc[2];
#pragma unroll
  for (int n = 0; n < 2; ++n)
#pragma unroll
    for (int r = 0; r < 16; ++r) oacc[n][r] = 0.f;
  float mrun = -3.0e38f, lrun = 0.f;

  const int srow = t >> 3;          // 0..15
  const int scol = (t & 7) * 16;    // byte col

  auto STAGE = [&](int buf, int kt) {
    const int kv0 = kt * 64;
#pragma unroll
    for (int i = 0; i < 4; ++i) {
      int row = i * 16 + srow;
      int cb = scol ^ ((row & 7) << 4);
      gl_lds16(Kb + (size_t)(kv0 + row) * EMB + head * DH + (cb >> 1),
               (char*)Klds[buf] + i * 2048 + t * 16);
      gl_lds16(Vt + (size_t)(head * DH + row) * SEQ + kv0 + (cb >> 1),
               (char*)Vlds[buf] + i * 2048 + t * 16);
    }
  };

  STAGE(0, 0);
  __syncthreads();

  int cur = 0;
  for (int kt = 0; kt < SEQ / 64; ++kt) {
    if (kt + 1 < SEQ / 64) STAGE(cur ^ 1, kt + 1);
    const int kv0 = kt * 64;

    // mask bias (exp2 domain), f32x4 per (tile, a): kv = kv0+32t+8a+4h+b
    f32x4 mbv[2][4];
#pragma unroll
    for (int tt = 0; tt < 2; ++tt)
#pragma unroll
      for (int a = 0; a < 4; ++a)
        mbv[tt][a] = *reinterpret_cast<const f32x4*>(mb2 + kv0 + tt * 32 + a * 8 + h * 4);

    // QK^T swapped: C[kv][q]; A = K-frag (row kv, d-octet), B = Q
    f32x16 s[2];
#pragma unroll
    for (int tt = 0; tt < 2; ++tt) {
#pragma unroll
      for (int r = 0; r < 16; ++r) s[tt][r] = 0.f;
#pragma unroll
      for (int ks = 0; ks < 4; ++ks) {
        int row = tt * 32 + lm;
        int cb = (ks * 32 + h * 16) ^ ((row & 7) << 4);
        short8 kf = *reinterpret_cast<const short8*>((const char*)Klds[cur] + row * 128 + cb);
        s[tt] = __builtin_amdgcn_mfma_f32_32x32x16_bf16(kf, qf[ks], s[tt], 0, 0, 0);
      }
    }

    // scale (exp2 domain) + mask bias
    const float sc2 = 0.125f * LOG2E;
#pragma unroll
    for (int tt = 0; tt < 2; ++tt)
#pragma unroll
      for (int r = 0; r < 16; ++r)
        s[tt][r] = fmaf(s[tt][r], sc2, mbv[tt][r >> 2][r & 3]);

    // row max: tree over 32 lane-local values + 1 cross-half shuffle
    float red[16];
#pragma unroll
    for (int r = 0; r < 16; ++r) red[r] = fmaxf(s[0][r], s[1][r]);
#pragma unroll
    for (int off = 8; off >= 1; off >>= 1)
#pragma unroll
      for (int r = 0; r < off; ++r) red[r] = fmaxf(red[r], red[r + off]);
    float pm = fmaxf(red[0], __shfl_xor(red[0], 32, 64));

    // defer-max: rescale O only when max grows past threshold
    if (!__all(pm <= mrun + 8.0f)) {
      float mnew = fmaxf(mrun, pm);
      float sf = __builtin_amdgcn_exp2f(mrun - mnew);
      mrun = mnew;
      lrun *= sf;
      bcs[wave][lm] = sf;   // broadcast per-q scale to C-layout lanes
      f32x4 sv[4];
#pragma unroll
      for (int a = 0; a < 4; ++a)
        sv[a] = *reinterpret_cast<const f32x4*>(&bcs[wave][a * 8 + h * 4]);
#pragma unroll
      for (int n = 0; n < 2; ++n)
#pragma unroll
        for (int r = 0; r < 16; ++r)
          oacc[n][r] *= sv[r >> 2][r & 3];
    }

    // P = exp2(s - m)
#pragma unroll
    for (int tt = 0; tt < 2; ++tt)
#pragma unroll
      for (int r = 0; r < 16; ++r)
        s[tt][r] = __builtin_amdgcn_exp2f(s[tt][r] - mrun);

    // row sum
    float rs[16];
#pragma unroll
    for (int r = 0; r < 16; ++r) rs[r] = s[0][r] + s[1][r];
#pragma unroll
    for (int off = 8; off >= 1; off >>= 1)
#pragma unroll
      for (int r = 0; r < off; ++r) rs[r] += rs[r + off];
    lrun += rs[0] + __shfl_xor(rs[0], 32, 64);

    // P -> bf16 A-fragments: cvt_pk pairs + permlane32_swap (T12).
    // permlane32_swap semantics: swaps VDST's UPPER 32 lanes with VSRC's
    // LOWER 32 lanes. With x = pack(kv{8a+4h+0,1}) for a=2ksl and
    // y = same for a=2ksl+1:
    //   x_new: h=0 -> kv{16ksl+0,1},  h=1 -> kv{16ksl+8,9}   = frag word 0
    //   y_new: h=0 -> kv{16ksl+4,5},  h=1 -> kv{16ksl+12,13} = frag word 2
    short8 pa[4];
#pragma unroll
    for (int tt = 0; tt < 2; ++tt) {
      uint32_t r0[4], r1[4];
#pragma unroll
      for (int a = 0; a < 4; ++a) {
        asm("v_cvt_pk_bf16_f32 %0, %1, %2" : "=v"(r0[a]) : "v"(s[tt][4 * a]), "v"(s[tt][4 * a + 1]));
        asm("v_cvt_pk_bf16_f32 %0, %1, %2" : "=v"(r1[a]) : "v"(s[tt][4 * a + 2]), "v"(s[tt][4 * a + 3]));
      }
#pragma unroll
      for (int ksl = 0; ksl < 2; ++ksl) {
        uint32_t x = r0[2 * ksl], y = r0[2 * ksl + 1];
        asm("v_permlane32_swap_b32 %0, %1" : "+v"(x), "+v"(y));
        uint32_t x2 = r1[2 * ksl], y2 = r1[2 * ksl + 1];
        asm("v_permlane32_swap_b32 %0, %1" : "+v"(x2), "+v"(y2));
        union { short8 s8; uint32_t u[4]; } pk;
        pk.u[0] = x; pk.u[1] = x2; pk.u[2] = y; pk.u[3] = y2;
        pa[tt * 2 + ksl] = pk.s8;
      }
    }

    // PV: oacc[n] += P * V  (B = V-frag from Vt tile, col d, k-octet kv)
#pragma unroll
    for (int n = 0; n < 2; ++n)
#pragma unroll
      for (int ks = 0; ks < 4; ++ks) {
        int row = n * 32 + lm;
        int cb = (ks * 32 + h * 16) ^ ((row & 7) << 4);
        short8 vf = *reinterpret_cast<const short8*>((const char*)Vlds[cur] + row * 128 + cb);
        oacc[n] = __builtin_amdgcn_mfma_f32_32x32x16_bf16(pa[ks], vf, oacc[n], 0, 0, 0);
      }

    __syncthreads();
    cur ^= 1;
  }

  // epilogue: broadcast 1/l to C-layout lanes, store bf16
  bcs[wave][lm] = __builtin_amdgcn_rcpf(lrun);
  f32x4 lv[4];
#pragma unroll
  for (int a = 0; a < 4; ++a)
    lv[a] = *reinterpret_cast<const f32x4*>(&bcs[wave][a * 8 + h * 4]);
#pragma unroll
  for (int n = 0; n < 2; ++n)
#pragma unroll
    for (int r = 0; r < 16; ++r) {
      int qq = q0 + (r & 3) + 8 * (r >> 2) + 4 * h;
      int dd = head * DH + n * 32 + lm;
      Out[(size_t)qq * EMB + dd] = f2bf(oacc[n][r] * lv[r >> 2][r & 3]);
    }
}

// ---------- launch ----------
extern "C" void kernel_launch(void* const* d_in, const int* in_sizes, int n_in,
                              void* d_out, int out_size, void* d_ws, size_t ws_size,
                              hipStream_t stream) {
  const float* x    = (const float*)d_in[0];
  const float* mask = (const float*)d_in[1];
  const float* Wq   = (const float*)d_in[2];
  const float* bq   = (const float*)d_in[3];
  const float* Wk   = (const float*)d_in[4];
  const float* bk   = (const float*)d_in[5];
  const float* Wv   = (const float*)d_in[6];
  const float* bv   = (const float*)d_in[7];
  const float* Wo   = (const float*)d_in[8];
  const float* bo   = (const float*)d_in[9];
  float* out = (float*)d_out;

  char* ws = (char*)d_ws;
  const size_t SZ_X = (size_t)SEQ * EMB * 2;
  const size_t SZ_W = (size_t)EMB * EMB * 2;
  unsigned short* xb  = (unsigned short*)(ws);
  unsigned short* wqb = (unsigned short*)(ws + SZ_X);
  unsigned short* wkb = (unsigned short*)(ws + SZ_X + SZ_W);
  unsigned short* wvb = (unsigned short*)(ws + SZ_X + 2 * SZ_W);
  unsigned short* wob = (unsigned short*)(ws + SZ_X + 3 * SZ_W);
  unsigned short* Qb  = (unsigned short*)(ws + SZ_X + 4 * SZ_W);
  unsigned short* Kbuf= (unsigned short*)(ws + 2 * SZ_X + 4 * SZ_W);
  unsigned short* Vb  = (unsigned short*)(ws + 3 * SZ_X + 4 * SZ_W);
  unsigned short* Vtb = (unsigned short*)(ws + 4 * SZ_X + 4 * SZ_W);
  unsigned short* Ab  = (unsigned short*)(ws + 5 * SZ_X + 4 * SZ_W);
  float* mb2          = (float*)(ws + 6 * SZ_X + 4 * SZ_W);

  cvt_kernel<<<1536, 256, 0, stream>>>(x, xb, SEQ * EMB);
  cvt4_kernel<<<dim3(288, 4), 256, 0, stream>>>(Wq, Wk, Wv, Wo, wqb, wkb, wvb, wob, EMB * EMB);
  mbias_kernel<<<16, 256, 0, stream>>>(mask, mb2, SEQ);

  qkv_gemm<<<dim3(SEQ / 128, EMB / 128, 3), 256, 0, stream>>>(
      xb, wqb, wkb, wvb, bq, bk, bv, Qb, Kbuf, Vb);

  transpose_kernel<<<dim3(EMB / 32, SEQ / 32), dim3(32, 8), 0, stream>>>(Vb, Vtb);

  attn_kernel<<<768, 128, 0, stream>>>(Qb, Kbuf, Vtb, mb2, Ab);

  gemm_wo<<<dim3(SEQ / 128, EMB / 128), 256, 0, stream>>>(Ab, wob, bo, out);
}

// Round 5
// 159.520 us; speedup vs baseline: 1.6143x; 1.0366x over previous
//
#include <hip/hip_runtime.h>
#include <stdint.h>
#include <stddef.h>

#define EMB 768
#define SEQ 4096
#define NH 12
#define DH 64
#define LOG2E 1.44269504f

typedef __attribute__((ext_vector_type(8))) short short8;
typedef __attribute__((ext_vector_type(4))) float f32x4;
typedef __attribute__((ext_vector_type(16))) float f32x16;
typedef __attribute__((ext_vector_type(2))) unsigned int uint32x2;

// ---------- helpers ----------
static __device__ __forceinline__ unsigned short f2bf(float f) {
  union { float f; uint32_t u; } v; v.f = f;
  uint32_t u = v.u;
  return (unsigned short)((u + 0x7FFFu + ((u >> 16) & 1u)) >> 16);
}

static __device__ __forceinline__ void gl_lds16(const void* g, void* l) {
  __builtin_amdgcn_global_load_lds(
      (const __attribute__((address_space(1))) uint32_t*)g,
      (__attribute__((address_space(3))) uint32_t*)l, 16, 0, 0);
}

// cross-half (lane i <-> lane i+32) combine via v_permlane32_swap_b32.
// Use the BUILTIN (not inline asm): passing the same value twice through two
// "+v" asm operands lets the compiler coalesce them into one register, which
// degenerates the swap (round-4 failure, absmax 3.8e-3). The builtin returns
// both post-swap values as distinct SSA results -> allocator guarantees
// distinct registers: r[0]=[v_lo,v_lo], r[1]=[v_hi,v_hi].
static __device__ __forceinline__ float xhalf_max(float v) {
  union { float f; unsigned int u; } x; x.f = v;
  uint32x2 r = __builtin_amdgcn_permlane32_swap(x.u, x.u, false, false);
  union { unsigned int u; float f; } a, b; a.u = r[0]; b.u = r[1];
  return fmaxf(a.f, b.f);
}
static __device__ __forceinline__ float xhalf_sum(float v) {
  union { float f; unsigned int u; } x; x.f = v;
  uint32x2 r = __builtin_amdgcn_permlane32_swap(x.u, x.u, false, false);
  union { unsigned int u; float f; } a, b; a.u = r[0]; b.u = r[1];
  return a.f + b.f;
}

// ---------- fp32 -> bf16 convert ----------
__global__ void cvt_kernel(const float* __restrict__ in,
                           unsigned short* __restrict__ out, int n) {
  int stride = gridDim.x * blockDim.x * 4;
  for (int i = (blockIdx.x * blockDim.x + threadIdx.x) * 4; i < n; i += stride) {
    float4 v = *reinterpret_cast<const float4*>(in + i);
    ushort4 o;
    o.x = f2bf(v.x); o.y = f2bf(v.y); o.z = f2bf(v.z); o.w = f2bf(v.w);
    *reinterpret_cast<ushort4*>(out + i) = o;
  }
}

// 4 weight matrices in one launch (blockIdx.y selects)
__global__ void cvt4_kernel(const float* __restrict__ i0, const float* __restrict__ i1,
                            const float* __restrict__ i2, const float* __restrict__ i3,
                            unsigned short* __restrict__ o0, unsigned short* __restrict__ o1,
                            unsigned short* __restrict__ o2, unsigned short* __restrict__ o3,
                            int n) {
  int y = blockIdx.y;
  const float* in = y == 0 ? i0 : y == 1 ? i1 : y == 2 ? i2 : i3;
  unsigned short* out = y == 0 ? o0 : y == 1 ? o1 : y == 2 ? o2 : o3;
  int stride = gridDim.x * blockDim.x * 4;
  for (int i = (blockIdx.x * blockDim.x + threadIdx.x) * 4; i < n; i += stride) {
    float4 v = *reinterpret_cast<const float4*>(in + i);
    ushort4 o;
    o.x = f2bf(v.x); o.y = f2bf(v.y); o.z = f2bf(v.z); o.w = f2bf(v.w);
    *reinterpret_cast<ushort4*>(out + i) = o;
  }
}

// mask -> additive bias in exp2 domain
__global__ void mbias_kernel(const float* __restrict__ mask, float* __restrict__ mb2, int n) {
  int i = blockIdx.x * blockDim.x + threadIdx.x;
  if (i < n) mb2[i] = -10000.f * (1.f - mask[i]) * LOG2E;
}

// ---------- GEMM core: C[M][N] = A[M][K] * W[N][K]^T + bias ----------
template <int OUT_F32>
static __device__ __forceinline__ void gemm128(
    const unsigned short* __restrict__ A, const unsigned short* __restrict__ W,
    const float* __restrict__ bias, void* __restrict__ Cout,
    int M, int N, int K, int bm, int bn) {
  __shared__ unsigned short Alds[128 * 64];
  __shared__ unsigned short Blds[128 * 64];
  const int t = threadIdx.x;
  const int lane = t & 63;
  const int wave = t >> 6;
  const int wr = wave >> 1, wc = wave & 1;
  const int lm = lane & 15, lg = lane >> 4;

  f32x4 acc[4][4];
#pragma unroll
  for (int i = 0; i < 4; ++i)
#pragma unroll
    for (int j = 0; j < 4; ++j) acc[i][j] = (f32x4){0.f, 0.f, 0.f, 0.f};

  const int srow = t >> 3;
  const int scsw = (t & 7) * 16;

  const int nK = K >> 6;
  for (int kt = 0; kt < nK; ++kt) {
    const int k0 = kt << 6;
#pragma unroll
    for (int i = 0; i < 4; ++i) {
      int row = i * 32 + srow;
      int cb = scsw ^ ((row & 7) << 4);
      gl_lds16(A + (size_t)(bm * 128 + row) * K + k0 + (cb >> 1),
               (char*)Alds + i * 4096 + t * 16);
      gl_lds16(W + (size_t)(bn * 128 + row) * K + k0 + (cb >> 1),
               (char*)Blds + i * 4096 + t * 16);
    }
    __syncthreads();
#pragma unroll
    for (int kk = 0; kk < 2; ++kk) {
      short8 af[4], bfr[4];
#pragma unroll
      for (int i = 0; i < 4; ++i) {
        int rowa = wr * 64 + i * 16 + lm;
        int cba = (kk * 64 + lg * 16) ^ ((rowa & 7) << 4);
        af[i] = *reinterpret_cast<const short8*>((const char*)Alds + rowa * 128 + cba);
        int rowb = wc * 64 + i * 16 + lm;
        int cbb = (kk * 64 + lg * 16) ^ ((rowb & 7) << 4);
        bfr[i] = *reinterpret_cast<const short8*>((const char*)Blds + rowb * 128 + cbb);
      }
#pragma unroll
      for (int i = 0; i < 4; ++i)
#pragma unroll
        for (int j = 0; j < 4; ++j)
          acc[i][j] = __builtin_amdgcn_mfma_f32_16x16x32_bf16(af[i], bfr[j], acc[i][j], 0, 0, 0);
    }
    __syncthreads();
  }
#pragma unroll
  for (int i = 0; i < 4; ++i) {
    int row0 = bm * 128 + wr * 64 + i * 16 + lg * 4;
#pragma unroll
    for (int j = 0; j < 4; ++j) {
      int col = bn * 128 + wc * 64 + j * 16 + lm;
      float b = bias[col];
#pragma unroll
      for (int r = 0; r < 4; ++r) {
        float v = acc[i][j][r] + b;
        if (OUT_F32)
          ((float*)Cout)[(size_t)(row0 + r) * N + col] = v;
        else
          ((unsigned short*)Cout)[(size_t)(row0 + r) * N + col] = f2bf(v);
      }
    }
  }
}

__global__ __launch_bounds__(256, 2) void gemm_wo(
    const unsigned short* __restrict__ A, const unsigned short* __restrict__ W,
    const float* __restrict__ bias, float* __restrict__ C) {
  gemm128<1>(A, W, bias, C, SEQ, EMB, EMB, blockIdx.x, blockIdx.y);
}

__global__ __launch_bounds__(256, 2) void qkv_gemm(
    const unsigned short* __restrict__ A,
    const unsigned short* __restrict__ W0, const unsigned short* __restrict__ W1,
    const unsigned short* __restrict__ W2,
    const float* __restrict__ b0, const float* __restrict__ b1, const float* __restrict__ b2,
    unsigned short* __restrict__ O0, unsigned short* __restrict__ O1,
    unsigned short* __restrict__ O2) {
  const int z = blockIdx.z;
  const unsigned short* W = z == 0 ? W0 : z == 1 ? W1 : W2;
  const float* bias = z == 0 ? b0 : z == 1 ? b1 : b2;
  unsigned short* O = z == 0 ? O0 : z == 1 ? O1 : O2;
  gemm128<0>(A, W, bias, O, SEQ, EMB, EMB, blockIdx.x, blockIdx.y);
}

// ---------- V transpose: V[SEQ][EMB] -> Vt[EMB][SEQ] (bf16) ----------
__global__ void transpose_kernel(const unsigned short* __restrict__ in,
                                 unsigned short* __restrict__ out) {
  __shared__ unsigned short tile[32][33];
  int tx = threadIdx.x, ty = threadIdx.y;   // 32 x 8
  int e0 = blockIdx.x * 32, s0 = blockIdx.y * 32;
#pragma unroll
  for (int i = 0; i < 4; ++i)
    tile[ty + i * 8][tx] = in[(size_t)(s0 + ty + i * 8) * EMB + e0 + tx];
  __syncthreads();
#pragma unroll
  for (int i = 0; i < 4; ++i)
    out[(size_t)(e0 + ty + i * 8) * SEQ + s0 + tx] = tile[tx][ty + i * 8];
}

// ---------- flash attention, swapped-QK^T 32x32 structure ----------
// grid: 768 blocks (64 q-blocks x 12 heads via bijective XCD swizzle),
// 2 waves/block, 32 q-rows/wave, KV tile = 64, double-buffered LDS.
__global__ __launch_bounds__(128, 2) void attn_kernel(
    const unsigned short* __restrict__ Q, const unsigned short* __restrict__ Kb,
    const unsigned short* __restrict__ Vt, const float* __restrict__ mb2,
    unsigned short* __restrict__ Out) {
  __shared__ unsigned short Klds[2][64 * 64];   // [kv][d], swizzled 128B rows
  __shared__ unsigned short Vlds[2][64 * 64];   // [d][kv], swizzled 128B rows
  __shared__ __align__(16) float bcs[2][32];    // per-wave broadcast scratch

  const int t = threadIdx.x;
  const int lane = t & 63;
  const int wave = t >> 6;
  const int o = blockIdx.x;
  const int wg = (o & 7) * 96 + (o >> 3);       // XCD swizzle (768 % 8 == 0)
  const int head = wg >> 6;
  const int q0 = (wg & 63) * 64 + wave * 32;
  const int lm = lane & 31;
  const int h = lane >> 5;

  // Q B-fragments (col = q = lm, k-octet = d = 16ks + 8h .. +8)
  short8 qf[4];
#pragma unroll
  for (int ks = 0; ks < 4; ++ks)
    qf[ks] = *reinterpret_cast<const short8*>(
        Q + (size_t)(q0 + lm) * EMB + head * DH + ks * 16 + h * 8);

  f32x16 oacc[2];
#pragma unroll
  for (int n = 0; n < 2; ++n)
#pragma unroll
    for (int r = 0; r < 16; ++r) oacc[n][r] = 0.f;
  float mrun = -3.0e38f, lrun = 0.f;

  const int srow = t >> 3;          // 0..15
  const int scol = (t & 7) * 16;    // byte col

  auto STAGE = [&](int buf, int kt) {
    const int kv0 = kt * 64;
#pragma unroll
    for (int i = 0; i < 4; ++i) {
      int row = i * 16 + srow;
      int cb = scol ^ ((row & 7) << 4);
      gl_lds16(Kb + (size_t)(kv0 + row) * EMB + head * DH + (cb >> 1),
               (char*)Klds[buf] + i * 2048 + t * 16);
      gl_lds16(Vt + (size_t)(head * DH + row) * SEQ + kv0 + (cb >> 1),
               (char*)Vlds[buf] + i * 2048 + t * 16);
    }
  };

  STAGE(0, 0);
  __syncthreads();

  int cur = 0;
  for (int kt = 0; kt < SEQ / 64; ++kt) {
    if (kt + 1 < SEQ / 64) STAGE(cur ^ 1, kt + 1);
    const int kv0 = kt * 64;

    // mask bias (exp2 domain), f32x4 per (tile, a): kv = kv0+32t+8a+4h+b
    f32x4 mbv[2][4];
#pragma unroll
    for (int tt = 0; tt < 2; ++tt)
#pragma unroll
      for (int a = 0; a < 4; ++a)
        mbv[tt][a] = *reinterpret_cast<const f32x4*>(mb2 + kv0 + tt * 32 + a * 8 + h * 4);

    // QK^T swapped: C[kv][q]; A = K-frag (row kv, d-octet), B = Q
    f32x16 s[2];
    __builtin_amdgcn_s_setprio(1);
#pragma unroll
    for (int tt = 0; tt < 2; ++tt) {
#pragma unroll
      for (int r = 0; r < 16; ++r) s[tt][r] = 0.f;
#pragma unroll
      for (int ks = 0; ks < 4; ++ks) {
        int row = tt * 32 + lm;
        int cb = (ks * 32 + h * 16) ^ ((row & 7) << 4);
        short8 kf = *reinterpret_cast<const short8*>((const char*)Klds[cur] + row * 128 + cb);
        s[tt] = __builtin_amdgcn_mfma_f32_32x32x16_bf16(kf, qf[ks], s[tt], 0, 0, 0);
      }
    }
    __builtin_amdgcn_s_setprio(0);

    // scale (exp2 domain) + mask bias
    const float sc2 = 0.125f * LOG2E;
#pragma unroll
    for (int tt = 0; tt < 2; ++tt)
#pragma unroll
      for (int r = 0; r < 16; ++r)
        s[tt][r] = fmaf(s[tt][r], sc2, mbv[tt][r >> 2][r & 3]);

    // row max: tree over 32 lane-local values + 1 cross-half permlane swap
    float red[16];
#pragma unroll
    for (int r = 0; r < 16; ++r) red[r] = fmaxf(s[0][r], s[1][r]);
#pragma unroll
    for (int off = 8; off >= 1; off >>= 1)
#pragma unroll
      for (int r = 0; r < off; ++r) red[r] = fmaxf(red[r], red[r + off]);
    float pm = xhalf_max(red[0]);

    // defer-max: rescale O only when max grows past threshold
    if (!__all(pm <= mrun + 8.0f)) {
      float mnew = fmaxf(mrun, pm);
      float sf = __builtin_amdgcn_exp2f(mrun - mnew);
      mrun = mnew;
      lrun *= sf;
      bcs[wave][lm] = sf;   // broadcast per-q scale to C-layout lanes
      f32x4 sv[4];
#pragma unroll
      for (int a = 0; a < 4; ++a)
        sv[a] = *reinterpret_cast<const f32x4*>(&bcs[wave][a * 8 + h * 4]);
#pragma unroll
      for (int n = 0; n < 2; ++n)
#pragma unroll
        for (int r = 0; r < 16; ++r)
          oacc[n][r] *= sv[r >> 2][r & 3];
    }

    // P = exp2(s - m)
#pragma unroll
    for (int tt = 0; tt < 2; ++tt)
#pragma unroll
      for (int r = 0; r < 16; ++r)
        s[tt][r] = __builtin_amdgcn_exp2f(s[tt][r] - mrun);

    // row sum
    float rs[16];
#pragma unroll
    for (int r = 0; r < 16; ++r) rs[r] = s[0][r] + s[1][r];
#pragma unroll
    for (int off = 8; off >= 1; off >>= 1)
#pragma unroll
      for (int r = 0; r < off; ++r) rs[r] += rs[r + off];
    lrun += xhalf_sum(rs[0]);

    // P -> bf16 A-fragments: cvt_pk pairs + permlane32_swap (T12).
    // permlane32_swap semantics: swaps VDST's UPPER 32 lanes with VSRC's
    // LOWER 32 lanes. With x = pack(kv{8a+4h+0,1}) for a=2ksl and
    // y = same for a=2ksl+1:
    //   x_new: h=0 -> kv{16ksl+0,1},  h=1 -> kv{16ksl+8,9}   = frag word 0
    //   y_new: h=0 -> kv{16ksl+4,5},  h=1 -> kv{16ksl+12,13} = frag word 2
    short8 pa[4];
#pragma unroll
    for (int tt = 0; tt < 2; ++tt) {
      uint32_t r0[4], r1[4];
#pragma unroll
      for (int a = 0; a < 4; ++a) {
        asm("v_cvt_pk_bf16_f32 %0, %1, %2" : "=v"(r0[a]) : "v"(s[tt][4 * a]), "v"(s[tt][4 * a + 1]));
        asm("v_cvt_pk_bf16_f32 %0, %1, %2" : "=v"(r1[a]) : "v"(s[tt][4 * a + 2]), "v"(s[tt][4 * a + 3]));
      }
#pragma unroll
      for (int ksl = 0; ksl < 2; ++ksl) {
        uint32x2 w0 = __builtin_amdgcn_permlane32_swap(r0[2 * ksl], r0[2 * ksl + 1], false, false);
        uint32x2 w1 = __builtin_amdgcn_permlane32_swap(r1[2 * ksl], r1[2 * ksl + 1], false, false);
        union { short8 s8; uint32_t u[4]; } pk;
        pk.u[0] = w0[0]; pk.u[1] = w1[0]; pk.u[2] = w0[1]; pk.u[3] = w1[1];
        pa[tt * 2 + ksl] = pk.s8;
      }
    }

    // PV: oacc[n] += P * V  (B = V-frag from Vt tile, col d, k-octet kv)
    __builtin_amdgcn_s_setprio(1);
#pragma unroll
    for (int n = 0; n < 2; ++n)
#pragma unroll
      for (int ks = 0; ks < 4; ++ks) {
        int row = n * 32 + lm;
        int cb = (ks * 32 + h * 16) ^ ((row & 7) << 4);
        short8 vf = *reinterpret_cast<const short8*>((const char*)Vlds[cur] + row * 128 + cb);
        oacc[n] = __builtin_amdgcn_mfma_f32_32x32x16_bf16(pa[ks], vf, oacc[n], 0, 0, 0);
      }
    __builtin_amdgcn_s_setprio(0);

    __syncthreads();
    cur ^= 1;
  }

  // epilogue: broadcast 1/l to C-layout lanes, store bf16
  bcs[wave][lm] = __builtin_amdgcn_rcpf(lrun);
  f32x4 lv[4];
#pragma unroll
  for (int a = 0; a < 4; ++a)
    lv[a] = *reinterpret_cast<const f32x4*>(&bcs[wave][a * 8 + h * 4]);
#pragma unroll
  for (int n = 0; n < 2; ++n)
#pragma unroll
    for (int r = 0; r < 16; ++r) {
      int qq = q0 + (r & 3) + 8 * (r >> 2) + 4 * h;
      int dd = head * DH + n * 32 + lm;
      Out[(size_t)qq * EMB + dd] = f2bf(oacc[n][r] * lv[r >> 2][r & 3]);
    }
}

// ---------- launch ----------
extern "C" void kernel_launch(void* const* d_in, const int* in_sizes, int n_in,
                              void* d_out, int out_size, void* d_ws, size_t ws_size,
                              hipStream_t stream) {
  const float* x    = (const float*)d_in[0];
  const float* mask = (const float*)d_in[1];
  const float* Wq   = (const float*)d_in[2];
  const float* bq   = (const float*)d_in[3];
  const float* Wk   = (const float*)d_in[4];
  const float* bk   = (const float*)d_in[5];
  const float* Wv   = (const float*)d_in[6];
  const float* bv   = (const float*)d_in[7];
  const float* Wo   = (const float*)d_in[8];
  const float* bo   = (const float*)d_in[9];
  float* out = (float*)d_out;

  char* ws = (char*)d_ws;
  const size_t SZ_X = (size_t)SEQ * EMB * 2;
  const size_t SZ_W = (size_t)EMB * EMB * 2;
  unsigned short* xb  = (unsigned short*)(ws);
  unsigned short* wqb = (unsigned short*)(ws + SZ_X);
  unsigned short* wkb = (unsigned short*)(ws + SZ_X + SZ_W);
  unsigned short* wvb = (unsigned short*)(ws + SZ_X + 2 * SZ_W);
  unsigned short* wob = (unsigned short*)(ws + SZ_X + 3 * SZ_W);
  unsigned short* Qb  = (unsigned short*)(ws + SZ_X + 4 * SZ_W);
  unsigned short* Kbuf= (unsigned short*)(ws + 2 * SZ_X + 4 * SZ_W);
  unsigned short* Vb  = (unsigned short*)(ws + 3 * SZ_X + 4 * SZ_W);
  unsigned short* Vtb = (unsigned short*)(ws + 4 * SZ_X + 4 * SZ_W);
  unsigned short* Ab  = (unsigned short*)(ws + 5 * SZ_X + 4 * SZ_W);
  float* mb2          = (float*)(ws + 6 * SZ_X + 4 * SZ_W);

  cvt_kernel<<<1536, 256, 0, stream>>>(x, xb, SEQ * EMB);
  cvt4_kernel<<<dim3(288, 4), 256, 0, stream>>>(Wq, Wk, Wv, Wo, wqb, wkb, wvb, wob, EMB * EMB);
  mbias_kernel<<<16, 256, 0, stream>>>(mask, mb2, SEQ);

  qkv_gemm<<<dim3(SEQ / 128, EMB / 128, 3), 256, 0, stream>>>(
      xb, wqb, wkb, wvb, bq, bk, bv, Qb, Kbuf, Vb);

  transpose_kernel<<<dim3(EMB / 32, SEQ / 32), dim3(32, 8), 0, stream>>>(Vb, Vtb);

  attn_kernel<<<768, 128, 0, stream>>>(Qb, Kbuf, Vtb, mb2, Ab);

  gemm_wo<<<dim3(SEQ / 128, EMB / 128), 256, 0, stream>>>(Ab, wob, bo, out);
}

// Round 6
// 157.242 us; speedup vs baseline: 1.6377x; 1.0145x over previous
//
#include <hip/hip_runtime.h>
#include <stdint.h>
#include <stddef.h>

#define EMB 768
#define SEQ 4096
#define NH 12
#define DH 64
#define LOG2E 1.44269504f

typedef __attribute__((ext_vector_type(8))) short short8;
typedef __attribute__((ext_vector_type(4))) float f32x4;
typedef __attribute__((ext_vector_type(16))) float f32x16;
typedef __attribute__((ext_vector_type(2))) unsigned int uint32x2;

// ---------- helpers ----------
static __device__ __forceinline__ unsigned short f2bf(float f) {
  union { float f; uint32_t u; } v; v.f = f;
  uint32_t u = v.u;
  return (unsigned short)((u + 0x7FFFu + ((u >> 16) & 1u)) >> 16);
}

static __device__ __forceinline__ void gl_lds16(const void* g, void* l) {
  __builtin_amdgcn_global_load_lds(
      (const __attribute__((address_space(1))) uint32_t*)g,
      (__attribute__((address_space(3))) uint32_t*)l, 16, 0, 0);
}
static __device__ __forceinline__ void gl_lds4(const void* g, void* l) {
  __builtin_amdgcn_global_load_lds(
      (const __attribute__((address_space(1))) uint32_t*)g,
      (__attribute__((address_space(3))) uint32_t*)l, 4, 0, 0);
}

// cross-half (lane i <-> lane i+32) combine via the permlane32_swap BUILTIN
// (inline asm with duplicated "+v" operands lets the allocator coalesce the
// two copies into one register -> degenerate swap; round-4 failure).
static __device__ __forceinline__ float xhalf_max(float v) {
  union { float f; unsigned int u; } x; x.f = v;
  uint32x2 r = __builtin_amdgcn_permlane32_swap(x.u, x.u, false, false);
  union { unsigned int u; float f; } a, b; a.u = r[0]; b.u = r[1];
  return fmaxf(a.f, b.f);
}
static __device__ __forceinline__ float xhalf_sum(float v) {
  union { float f; unsigned int u; } x; x.f = v;
  uint32x2 r = __builtin_amdgcn_permlane32_swap(x.u, x.u, false, false);
  union { unsigned int u; float f; } a, b; a.u = r[0]; b.u = r[1];
  return a.f + b.f;
}

// ---------- fp32 -> bf16 convert ----------
__global__ void cvt_kernel(const float* __restrict__ in,
                           unsigned short* __restrict__ out, int n) {
  int stride = gridDim.x * blockDim.x * 4;
  for (int i = (blockIdx.x * blockDim.x + threadIdx.x) * 4; i < n; i += stride) {
    float4 v = *reinterpret_cast<const float4*>(in + i);
    ushort4 o;
    o.x = f2bf(v.x); o.y = f2bf(v.y); o.z = f2bf(v.z); o.w = f2bf(v.w);
    *reinterpret_cast<ushort4*>(out + i) = o;
  }
}

// 4 weight matrices in one launch (blockIdx.y selects)
__global__ void cvt4_kernel(const float* __restrict__ i0, const float* __restrict__ i1,
                            const float* __restrict__ i2, const float* __restrict__ i3,
                            unsigned short* __restrict__ o0, unsigned short* __restrict__ o1,
                            unsigned short* __restrict__ o2, unsigned short* __restrict__ o3,
                            int n) {
  int y = blockIdx.y;
  const float* in = y == 0 ? i0 : y == 1 ? i1 : y == 2 ? i2 : i3;
  unsigned short* out = y == 0 ? o0 : y == 1 ? o1 : y == 2 ? o2 : o3;
  int stride = gridDim.x * blockDim.x * 4;
  for (int i = (blockIdx.x * blockDim.x + threadIdx.x) * 4; i < n; i += stride) {
    float4 v = *reinterpret_cast<const float4*>(in + i);
    ushort4 o;
    o.x = f2bf(v.x); o.y = f2bf(v.y); o.z = f2bf(v.z); o.w = f2bf(v.w);
    *reinterpret_cast<ushort4*>(out + i) = o;
  }
}

// mask -> additive bias in exp2 domain
__global__ void mbias_kernel(const float* __restrict__ mask, float* __restrict__ mb2, int n) {
  int i = blockIdx.x * blockDim.x + threadIdx.x;
  if (i < n) mb2[i] = -10000.f * (1.f - mask[i]) * LOG2E;
}

// ---------- GEMM core: C[M][N] = A[M][K] * W[N][K]^T + bias ----------
template <int OUT_F32>
static __device__ __forceinline__ void gemm128(
    const unsigned short* __restrict__ A, const unsigned short* __restrict__ W,
    const float* __restrict__ bias, void* __restrict__ Cout,
    int M, int N, int K, int bm, int bn) {
  __shared__ unsigned short Alds[128 * 64];
  __shared__ unsigned short Blds[128 * 64];
  const int t = threadIdx.x;
  const int lane = t & 63;
  const int wave = t >> 6;
  const int wr = wave >> 1, wc = wave & 1;
  const int lm = lane & 15, lg = lane >> 4;

  f32x4 acc[4][4];
#pragma unroll
  for (int i = 0; i < 4; ++i)
#pragma unroll
    for (int j = 0; j < 4; ++j) acc[i][j] = (f32x4){0.f, 0.f, 0.f, 0.f};

  const int srow = t >> 3;
  const int scsw = (t & 7) * 16;

  const int nK = K >> 6;
  for (int kt = 0; kt < nK; ++kt) {
    const int k0 = kt << 6;
#pragma unroll
    for (int i = 0; i < 4; ++i) {
      int row = i * 32 + srow;
      int cb = scsw ^ ((row & 7) << 4);
      gl_lds16(A + (size_t)(bm * 128 + row) * K + k0 + (cb >> 1),
               (char*)Alds + i * 4096 + t * 16);
      gl_lds16(W + (size_t)(bn * 128 + row) * K + k0 + (cb >> 1),
               (char*)Blds + i * 4096 + t * 16);
    }
    __syncthreads();
#pragma unroll
    for (int kk = 0; kk < 2; ++kk) {
      short8 af[4], bfr[4];
#pragma unroll
      for (int i = 0; i < 4; ++i) {
        int rowa = wr * 64 + i * 16 + lm;
        int cba = (kk * 64 + lg * 16) ^ ((rowa & 7) << 4);
        af[i] = *reinterpret_cast<const short8*>((const char*)Alds + rowa * 128 + cba);
        int rowb = wc * 64 + i * 16 + lm;
        int cbb = (kk * 64 + lg * 16) ^ ((rowb & 7) << 4);
        bfr[i] = *reinterpret_cast<const short8*>((const char*)Blds + rowb * 128 + cbb);
      }
#pragma unroll
      for (int i = 0; i < 4; ++i)
#pragma unroll
        for (int j = 0; j < 4; ++j)
          acc[i][j] = __builtin_amdgcn_mfma_f32_16x16x32_bf16(af[i], bfr[j], acc[i][j], 0, 0, 0);
    }
    __syncthreads();
  }
#pragma unroll
  for (int i = 0; i < 4; ++i) {
    int row0 = bm * 128 + wr * 64 + i * 16 + lg * 4;
#pragma unroll
    for (int j = 0; j < 4; ++j) {
      int col = bn * 128 + wc * 64 + j * 16 + lm;
      float b = bias[col];
#pragma unroll
      for (int r = 0; r < 4; ++r) {
        float v = acc[i][j][r] + b;
        if (OUT_F32)
          ((float*)Cout)[(size_t)(row0 + r) * N + col] = v;
        else
          ((unsigned short*)Cout)[(size_t)(row0 + r) * N + col] = f2bf(v);
      }
    }
  }
}

__global__ __launch_bounds__(256, 2) void gemm_wo(
    const unsigned short* __restrict__ A, const unsigned short* __restrict__ W,
    const float* __restrict__ bias, float* __restrict__ C) {
  gemm128<1>(A, W, bias, C, SEQ, EMB, EMB, blockIdx.x, blockIdx.y);
}

__global__ __launch_bounds__(256, 2) void qkv_gemm(
    const unsigned short* __restrict__ A,
    const unsigned short* __restrict__ W0, const unsigned short* __restrict__ W1,
    const unsigned short* __restrict__ W2,
    const float* __restrict__ b0, const float* __restrict__ b1, const float* __restrict__ b2,
    unsigned short* __restrict__ O0, unsigned short* __restrict__ O1,
    unsigned short* __restrict__ O2) {
  const int z = blockIdx.z;
  const unsigned short* W = z == 0 ? W0 : z == 1 ? W1 : W2;
  const float* bias = z == 0 ? b0 : z == 1 ? b1 : b2;
  unsigned short* O = z == 0 ? O0 : z == 1 ? O1 : O2;
  gemm128<0>(A, W, bias, O, SEQ, EMB, EMB, blockIdx.x, blockIdx.y);
}

// ---------- V transpose: V[SEQ][EMB] -> Vt[EMB][SEQ] (bf16) ----------
__global__ void transpose_kernel(const unsigned short* __restrict__ in,
                                 unsigned short* __restrict__ out) {
  __shared__ unsigned short tile[32][33];
  int tx = threadIdx.x, ty = threadIdx.y;   // 32 x 8
  int e0 = blockIdx.x * 32, s0 = blockIdx.y * 32;
#pragma unroll
  for (int i = 0; i < 4; ++i)
    tile[ty + i * 8][tx] = in[(size_t)(s0 + ty + i * 8) * EMB + e0 + tx];
  __syncthreads();
#pragma unroll
  for (int i = 0; i < 4; ++i)
    out[(size_t)(e0 + ty + i * 8) * SEQ + s0 + tx] = tile[tx][ty + i * 8];
}

// ---------- flash attention, swapped-QK^T 32x32, counted-vmcnt pipeline ----
// grid: 768 blocks (64 q-blocks x 12 heads, XCD swizzle), 2 waves/block,
// 32 q-rows/wave, KV tile = 64. TRIPLE-buffered LDS, prefetch distance 2,
// one raw s_barrier per iter preceded by s_waitcnt vmcnt(9) (the 9 newest
// vmem ops = this wave's in-flight STAGE batch stay in flight; the batch
// being consumed was issued 2 iterations ago). Mask bias is staged through
// LDS as part of the batch so the vmem count per iteration is exact.
__global__ __launch_bounds__(128, 2) void attn_kernel(
    const unsigned short* __restrict__ Q, const unsigned short* __restrict__ Kb,
    const unsigned short* __restrict__ Vt, const float* __restrict__ mb2,
    unsigned short* __restrict__ Out) {
  __shared__ unsigned short Klds[3][64 * 64];   // [kv][d], swizzled 128B rows
  __shared__ unsigned short Vlds[3][64 * 64];   // [d][kv], swizzled 128B rows
  __shared__ __align__(16) float msk[3][64];    // staged mask bias (exp2 dom)
  __shared__ __align__(16) float bcs[2][32];    // per-wave broadcast scratch

  const int t = threadIdx.x;
  const int lane = t & 63;
  const int wave = t >> 6;
  const int o = blockIdx.x;
  const int wg = (o & 7) * 96 + (o >> 3);       // XCD swizzle (768 % 8 == 0)
  const int head = wg >> 6;
  const int q0 = (wg & 63) * 64 + wave * 32;
  const int lm = lane & 31;
  const int h = lane >> 5;

  // Q B-fragments (col = q = lm, k-octet = d = 16ks + 8h .. +8)
  short8 qf[4];
#pragma unroll
  for (int ks = 0; ks < 4; ++ks)
    qf[ks] = *reinterpret_cast<const short8*>(
        Q + (size_t)(q0 + lm) * EMB + head * DH + ks * 16 + h * 8);

  f32x16 oacc[2];
#pragma unroll
  for (int n = 0; n < 2; ++n)
#pragma unroll
    for (int r = 0; r < 16; ++r) oacc[n][r] = 0.f;
  float mrun = -3.0e38f, lrun = 0.f;

  const int srow = t >> 3;          // 0..15
  const int scol = (t & 7) * 16;    // byte col

  // 9 vmem ops per wave per STAGE: 8x gl_lds16 (K,V) + 1x gl_lds4 (mask)
  auto STAGE = [&](int buf, int kt2) {
    const int kv0 = kt2 * 64;
#pragma unroll
    for (int i = 0; i < 4; ++i) {
      int row = i * 16 + srow;
      int cb = scol ^ ((row & 7) << 4);
      gl_lds16(Kb + (size_t)(kv0 + row) * EMB + head * DH + (cb >> 1),
               (char*)Klds + buf * 8192 + i * 2048 + t * 16);
      gl_lds16(Vt + (size_t)(head * DH + row) * SEQ + kv0 + (cb >> 1),
               (char*)Vlds + buf * 8192 + i * 2048 + t * 16);
    }
    // both waves write identical values - benign duplicate
    gl_lds4(mb2 + kv0 + lane, &msk[buf][0]);
  };

  constexpr int NT = SEQ / 64;
  STAGE(0, 0);
  STAGE(1, 1);

  for (int kt = 0; kt < NT; ++kt) {
    // wait for the batch staged 2 iterations ago; keep the newest batch
    // (and on the final iteration, drain everything)
    if (kt < NT - 1) {
      asm volatile("s_waitcnt vmcnt(9)" ::: "memory");
    } else {
      asm volatile("s_waitcnt vmcnt(0)" ::: "memory");
    }
    __builtin_amdgcn_s_barrier();
    if (kt + 2 < NT) STAGE((kt + 2) % 3, kt + 2);
    const int cur = kt % 3;

    // mask bias from LDS (uniform per 32-lane half -> broadcast reads)
    f32x4 mbv[2][4];
#pragma unroll
    for (int tt = 0; tt < 2; ++tt)
#pragma unroll
      for (int a = 0; a < 4; ++a)
        mbv[tt][a] = *reinterpret_cast<const f32x4*>(&msk[cur][tt * 32 + a * 8 + h * 4]);

    // QK^T swapped: C[kv][q]; A = K-frag (row kv, d-octet), B = Q
    f32x16 s[2];
    __builtin_amdgcn_s_setprio(1);
#pragma unroll
    for (int tt = 0; tt < 2; ++tt) {
#pragma unroll
      for (int r = 0; r < 16; ++r) s[tt][r] = 0.f;
#pragma unroll
      for (int ks = 0; ks < 4; ++ks) {
        int row = tt * 32 + lm;
        int cb = (ks * 32 + h * 16) ^ ((row & 7) << 4);
        short8 kf = *reinterpret_cast<const short8*>((const char*)Klds + cur * 8192 + row * 128 + cb);
        s[tt] = __builtin_amdgcn_mfma_f32_32x32x16_bf16(kf, qf[ks], s[tt], 0, 0, 0);
      }
    }
    __builtin_amdgcn_s_setprio(0);

    // scale (exp2 domain) + mask bias
    const float sc2 = 0.125f * LOG2E;
#pragma unroll
    for (int tt = 0; tt < 2; ++tt)
#pragma unroll
      for (int r = 0; r < 16; ++r)
        s[tt][r] = fmaf(s[tt][r], sc2, mbv[tt][r >> 2][r & 3]);

    // row max: tree over 32 lane-local values + 1 cross-half permlane swap
    float red[16];
#pragma unroll
    for (int r = 0; r < 16; ++r) red[r] = fmaxf(s[0][r], s[1][r]);
#pragma unroll
    for (int off = 8; off >= 1; off >>= 1)
#pragma unroll
      for (int r = 0; r < off; ++r) red[r] = fmaxf(red[r], red[r + off]);
    float pm = xhalf_max(red[0]);

    // defer-max: rescale O only when max grows past threshold
    if (!__all(pm <= mrun + 8.0f)) {
      float mnew = fmaxf(mrun, pm);
      float sf = __builtin_amdgcn_exp2f(mrun - mnew);
      mrun = mnew;
      lrun *= sf;
      bcs[wave][lm] = sf;   // broadcast per-q scale to C-layout lanes
      f32x4 sv[4];
#pragma unroll
      for (int a = 0; a < 4; ++a)
        sv[a] = *reinterpret_cast<const f32x4*>(&bcs[wave][a * 8 + h * 4]);
#pragma unroll
      for (int n = 0; n < 2; ++n)
#pragma unroll
        for (int r = 0; r < 16; ++r)
          oacc[n][r] *= sv[r >> 2][r & 3];
    }

    // P = exp2(s - m)
#pragma unroll
    for (int tt = 0; tt < 2; ++tt)
#pragma unroll
      for (int r = 0; r < 16; ++r)
        s[tt][r] = __builtin_amdgcn_exp2f(s[tt][r] - mrun);

    // row sum
    float rs[16];
#pragma unroll
    for (int r = 0; r < 16; ++r) rs[r] = s[0][r] + s[1][r];
#pragma unroll
    for (int off = 8; off >= 1; off >>= 1)
#pragma unroll
      for (int r = 0; r < off; ++r) rs[r] += rs[r + off];
    lrun += xhalf_sum(rs[0]);

    // P -> bf16 A-fragments: cvt_pk pairs + permlane32_swap (T12)
    short8 pa[4];
#pragma unroll
    for (int tt = 0; tt < 2; ++tt) {
      uint32_t r0[4], r1[4];
#pragma unroll
      for (int a = 0; a < 4; ++a) {
        asm("v_cvt_pk_bf16_f32 %0, %1, %2" : "=v"(r0[a]) : "v"(s[tt][4 * a]), "v"(s[tt][4 * a + 1]));
        asm("v_cvt_pk_bf16_f32 %0, %1, %2" : "=v"(r1[a]) : "v"(s[tt][4 * a + 2]), "v"(s[tt][4 * a + 3]));
      }
#pragma unroll
      for (int ksl = 0; ksl < 2; ++ksl) {
        uint32x2 w0 = __builtin_amdgcn_permlane32_swap(r0[2 * ksl], r0[2 * ksl + 1], false, false);
        uint32x2 w1 = __builtin_amdgcn_permlane32_swap(r1[2 * ksl], r1[2 * ksl + 1], false, false);
        union { short8 s8; uint32_t u[4]; } pk;
        pk.u[0] = w0[0]; pk.u[1] = w1[0]; pk.u[2] = w0[1]; pk.u[3] = w1[1];
        pa[tt * 2 + ksl] = pk.s8;
      }
    }

    // PV: oacc[n] += P * V  (B = V-frag from Vt tile, col d, k-octet kv)
    __builtin_amdgcn_s_setprio(1);
#pragma unroll
    for (int n = 0; n < 2; ++n)
#pragma unroll
      for (int ks = 0; ks < 4; ++ks) {
        int row = n * 32 + lm;
        int cb = (ks * 32 + h * 16) ^ ((row & 7) << 4);
        short8 vf = *reinterpret_cast<const short8*>((const char*)Vlds + cur * 8192 + row * 128 + cb);
        oacc[n] = __builtin_amdgcn_mfma_f32_32x32x16_bf16(pa[ks], vf, oacc[n], 0, 0, 0);
      }
    __builtin_amdgcn_s_setprio(0);
  }

  // epilogue: broadcast 1/l to C-layout lanes, store bf16
  bcs[wave][lm] = __builtin_amdgcn_rcpf(lrun);
  f32x4 lv[4];
#pragma unroll
  for (int a = 0; a < 4; ++a)
    lv[a] = *reinterpret_cast<const f32x4*>(&bcs[wave][a * 8 + h * 4]);
#pragma unroll
  for (int n = 0; n < 2; ++n)
#pragma unroll
    for (int r = 0; r < 16; ++r) {
      int qq = q0 + (r & 3) + 8 * (r >> 2) + 4 * h;
      int dd = head * DH + n * 32 + lm;
      Out[(size_t)qq * EMB + dd] = f2bf(oacc[n][r] * lv[r >> 2][r & 3]);
    }
}

// ---------- launch ----------
extern "C" void kernel_launch(void* const* d_in, const int* in_sizes, int n_in,
                              void* d_out, int out_size, void* d_ws, size_t ws_size,
                              hipStream_t stream) {
  const float* x    = (const float*)d_in[0];
  const float* mask = (const float*)d_in[1];
  const float* Wq   = (const float*)d_in[2];
  const float* bq   = (const float*)d_in[3];
  const float* Wk   = (const float*)d_in[4];
  const float* bk   = (const float*)d_in[5];
  const float* Wv   = (const float*)d_in[6];
  const float* bv   = (const float*)d_in[7];
  const float* Wo   = (const float*)d_in[8];
  const float* bo   = (const float*)d_in[9];
  float* out = (float*)d_out;

  char* ws = (char*)d_ws;
  const size_t SZ_X = (size_t)SEQ * EMB * 2;
  const size_t SZ_W = (size_t)EMB * EMB * 2;
  unsigned short* xb  = (unsigned short*)(ws);
  unsigned short* wqb = (unsigned short*)(ws + SZ_X);
  unsigned short* wkb = (unsigned short*)(ws + SZ_X + SZ_W);
  unsigned short* wvb = (unsigned short*)(ws + SZ_X + 2 * SZ_W);
  unsigned short* wob = (unsigned short*)(ws + SZ_X + 3 * SZ_W);
  unsigned short* Qb  = (unsigned short*)(ws + SZ_X + 4 * SZ_W);
  unsigned short* Kbuf= (unsigned short*)(ws + 2 * SZ_X + 4 * SZ_W);
  unsigned short* Vb  = (unsigned short*)(ws + 3 * SZ_X + 4 * SZ_W);
  unsigned short* Vtb = (unsigned short*)(ws + 4 * SZ_X + 4 * SZ_W);
  unsigned short* Ab  = (unsigned short*)(ws + 5 * SZ_X + 4 * SZ_W);
  float* mb2          = (float*)(ws + 6 * SZ_X + 4 * SZ_W);

  cvt_kernel<<<1536, 256, 0, stream>>>(x, xb, SEQ * EMB);
  cvt4_kernel<<<dim3(288, 4), 256, 0, stream>>>(Wq, Wk, Wv, Wo, wqb, wkb, wvb, wob, EMB * EMB);
  mbias_kernel<<<16, 256, 0, stream>>>(mask, mb2, SEQ);

  qkv_gemm<<<dim3(SEQ / 128, EMB / 128, 3), 256, 0, stream>>>(
      xb, wqb, wkb, wvb, bq, bk, bv, Qb, Kbuf, Vb);

  transpose_kernel<<<dim3(EMB / 32, SEQ / 32), dim3(32, 8), 0, stream>>>(Vb, Vtb);

  attn_kernel<<<768, 128, 0, stream>>>(Qb, Kbuf, Vtb, mb2, Ab);

  gemm_wo<<<dim3(SEQ / 128, EMB / 128), 256, 0, stream>>>(Ab, wob, bo, out);
}

// Round 7
// 145.378 us; speedup vs baseline: 1.7713x; 1.0816x over previous
//
#include <hip/hip_runtime.h>
#include <stdint.h>
#include <stddef.h>

#define EMB 768
#define SEQ 4096
#define NH 12
#define DH 64
#define LOG2E 1.44269504f
#define KVB 32
#define HALF (SEQ / 2)
#define NBLK ((SEQ / 64) * NH * 2)   // 1536 split-attn blocks

typedef __attribute__((ext_vector_type(8))) short short8;
typedef __attribute__((ext_vector_type(4))) float f32x4;
typedef __attribute__((ext_vector_type(16))) float f32x16;
typedef __attribute__((ext_vector_type(2))) unsigned int uint32x2;

// ---------- helpers ----------
static __device__ __forceinline__ unsigned short f2bf(float f) {
  union { float f; uint32_t u; } v; v.f = f;
  uint32_t u = v.u;
  return (unsigned short)((u + 0x7FFFu + ((u >> 16) & 1u)) >> 16);
}

static __device__ __forceinline__ void gl_lds16(const void* g, void* l) {
  __builtin_amdgcn_global_load_lds(
      (const __attribute__((address_space(1))) uint32_t*)g,
      (__attribute__((address_space(3))) uint32_t*)l, 16, 0, 0);
}
static __device__ __forceinline__ void gl_lds4(const void* g, void* l) {
  __builtin_amdgcn_global_load_lds(
      (const __attribute__((address_space(1))) uint32_t*)g,
      (__attribute__((address_space(3))) uint32_t*)l, 4, 0, 0);
}

// cross-half combine via the permlane32_swap BUILTIN (asm with duplicated
// "+v" operands coalesces registers -> degenerate swap; round-4 failure).
static __device__ __forceinline__ float xhalf_max(float v) {
  union { float f; unsigned int u; } x; x.f = v;
  uint32x2 r = __builtin_amdgcn_permlane32_swap(x.u, x.u, false, false);
  union { unsigned int u; float f; } a, b; a.u = r[0]; b.u = r[1];
  return fmaxf(a.f, b.f);
}
static __device__ __forceinline__ float xhalf_sum(float v) {
  union { float f; unsigned int u; } x; x.f = v;
  uint32x2 r = __builtin_amdgcn_permlane32_swap(x.u, x.u, false, false);
  union { unsigned int u; float f; } a, b; a.u = r[0]; b.u = r[1];
  return a.f + b.f;
}

// ---------- fp32 -> bf16 convert ----------
__global__ void cvt_kernel(const float* __restrict__ in,
                           unsigned short* __restrict__ out, int n) {
  int stride = gridDim.x * blockDim.x * 4;
  for (int i = (blockIdx.x * blockDim.x + threadIdx.x) * 4; i < n; i += stride) {
    float4 v = *reinterpret_cast<const float4*>(in + i);
    ushort4 o;
    o.x = f2bf(v.x); o.y = f2bf(v.y); o.z = f2bf(v.z); o.w = f2bf(v.w);
    *reinterpret_cast<ushort4*>(out + i) = o;
  }
}

__global__ void cvt4_kernel(const float* __restrict__ i0, const float* __restrict__ i1,
                            const float* __restrict__ i2, const float* __restrict__ i3,
                            unsigned short* __restrict__ o0, unsigned short* __restrict__ o1,
                            unsigned short* __restrict__ o2, unsigned short* __restrict__ o3,
                            int n) {
  int y = blockIdx.y;
  const float* in = y == 0 ? i0 : y == 1 ? i1 : y == 2 ? i2 : i3;
  unsigned short* out = y == 0 ? o0 : y == 1 ? o1 : y == 2 ? o2 : o3;
  int stride = gridDim.x * blockDim.x * 4;
  for (int i = (blockIdx.x * blockDim.x + threadIdx.x) * 4; i < n; i += stride) {
    float4 v = *reinterpret_cast<const float4*>(in + i);
    ushort4 o;
    o.x = f2bf(v.x); o.y = f2bf(v.y); o.z = f2bf(v.z); o.w = f2bf(v.w);
    *reinterpret_cast<ushort4*>(out + i) = o;
  }
}

// mask -> additive bias in exp2 domain
__global__ void mbias_kernel(const float* __restrict__ mask, float* __restrict__ mb2, int n) {
  int i = blockIdx.x * blockDim.x + threadIdx.x;
  if (i < n) mb2[i] = -10000.f * (1.f - mask[i]) * LOG2E;
}

// ---------- GEMM core: C[M][N] = A[M][K] * W[N][K]^T + bias ----------
template <int OUT_F32>
static __device__ __forceinline__ void gemm128(
    const unsigned short* __restrict__ A, const unsigned short* __restrict__ W,
    const float* __restrict__ bias, void* __restrict__ Cout,
    int M, int N, int K, int bm, int bn) {
  __shared__ unsigned short Alds[128 * 64];
  __shared__ unsigned short Blds[128 * 64];
  const int t = threadIdx.x;
  const int lane = t & 63;
  const int wave = t >> 6;
  const int wr = wave >> 1, wc = wave & 1;
  const int lm = lane & 15, lg = lane >> 4;

  f32x4 acc[4][4];
#pragma unroll
  for (int i = 0; i < 4; ++i)
#pragma unroll
    for (int j = 0; j < 4; ++j) acc[i][j] = (f32x4){0.f, 0.f, 0.f, 0.f};

  const int srow = t >> 3;
  const int scsw = (t & 7) * 16;

  const int nK = K >> 6;
  for (int kt = 0; kt < nK; ++kt) {
    const int k0 = kt << 6;
#pragma unroll
    for (int i = 0; i < 4; ++i) {
      int row = i * 32 + srow;
      int cb = scsw ^ ((row & 7) << 4);
      gl_lds16(A + (size_t)(bm * 128 + row) * K + k0 + (cb >> 1),
               (char*)Alds + i * 4096 + t * 16);
      gl_lds16(W + (size_t)(bn * 128 + row) * K + k0 + (cb >> 1),
               (char*)Blds + i * 4096 + t * 16);
    }
    __syncthreads();
#pragma unroll
    for (int kk = 0; kk < 2; ++kk) {
      short8 af[4], bfr[4];
#pragma unroll
      for (int i = 0; i < 4; ++i) {
        int rowa = wr * 64 + i * 16 + lm;
        int cba = (kk * 64 + lg * 16) ^ ((rowa & 7) << 4);
        af[i] = *reinterpret_cast<const short8*>((const char*)Alds + rowa * 128 + cba);
        int rowb = wc * 64 + i * 16 + lm;
        int cbb = (kk * 64 + lg * 16) ^ ((rowb & 7) << 4);
        bfr[i] = *reinterpret_cast<const short8*>((const char*)Blds + rowb * 128 + cbb);
      }
#pragma unroll
      for (int i = 0; i < 4; ++i)
#pragma unroll
        for (int j = 0; j < 4; ++j)
          acc[i][j] = __builtin_amdgcn_mfma_f32_16x16x32_bf16(af[i], bfr[j], acc[i][j], 0, 0, 0);
    }
    __syncthreads();
  }
#pragma unroll
  for (int i = 0; i < 4; ++i) {
    int row0 = bm * 128 + wr * 64 + i * 16 + lg * 4;
#pragma unroll
    for (int j = 0; j < 4; ++j) {
      int col = bn * 128 + wc * 64 + j * 16 + lm;
      float b = bias[col];
#pragma unroll
      for (int r = 0; r < 4; ++r) {
        float v = acc[i][j][r] + b;
        if (OUT_F32)
          ((float*)Cout)[(size_t)(row0 + r) * N + col] = v;
        else
          ((unsigned short*)Cout)[(size_t)(row0 + r) * N + col] = f2bf(v);
      }
    }
  }
}

__global__ __launch_bounds__(256, 2) void gemm_wo(
    const unsigned short* __restrict__ A, const unsigned short* __restrict__ W,
    const float* __restrict__ bias, float* __restrict__ C) {
  gemm128<1>(A, W, bias, C, SEQ, EMB, EMB, blockIdx.x, blockIdx.y);
}

__global__ __launch_bounds__(256, 2) void qkv_gemm(
    const unsigned short* __restrict__ A,
    const unsigned short* __restrict__ W0, const unsigned short* __restrict__ W1,
    const unsigned short* __restrict__ W2,
    const float* __restrict__ b0, const float* __restrict__ b1, const float* __restrict__ b2,
    unsigned short* __restrict__ O0, unsigned short* __restrict__ O1,
    unsigned short* __restrict__ O2) {
  const int z = blockIdx.z;
  const unsigned short* W = z == 0 ? W0 : z == 1 ? W1 : W2;
  const float* bias = z == 0 ? b0 : z == 1 ? b1 : b2;
  unsigned short* O = z == 0 ? O0 : z == 1 ? O1 : O2;
  gemm128<0>(A, W, bias, O, SEQ, EMB, EMB, blockIdx.x, blockIdx.y);
}

// ---------- V transpose: V[SEQ][EMB] -> Vt[EMB][SEQ] (bf16) ----------
__global__ void transpose_kernel(const unsigned short* __restrict__ in,
                                 unsigned short* __restrict__ out) {
  __shared__ unsigned short tile[32][33];
  int tx = threadIdx.x, ty = threadIdx.y;   // 32 x 8
  int e0 = blockIdx.x * 32, s0 = blockIdx.y * 32;
#pragma unroll
  for (int i = 0; i < 4; ++i)
    tile[ty + i * 8][tx] = in[(size_t)(s0 + ty + i * 8) * EMB + e0 + tx];
  __syncthreads();
#pragma unroll
  for (int i = 0; i < 4; ++i)
    out[(size_t)(e0 + ty + i * 8) * SEQ + s0 + tx] = tile[tx][ty + i * 8];
}

// ---------- flash attention, KV-split x2, KVB=32, triple-buffer ----------
// grid: 1536 blocks = 64 qb x 12 heads x 2 kv-halves (XCD swizzle),
// 2 waves/block, 32 q-rows/wave. LDS 24.6KB -> 6 blocks/CU (12 waves/CU).
// Partial (O, m, l) to workspace; merge_kernel combines the two halves.
__global__ __launch_bounds__(128, 3) void attn_kernel(
    const unsigned short* __restrict__ Q, const unsigned short* __restrict__ Kb,
    const unsigned short* __restrict__ Vt, const float* __restrict__ mb2,
    float* __restrict__ opart, float* __restrict__ mpart,
    float* __restrict__ lpart) {
  __shared__ unsigned short Klds[3][KVB * DH];   // [kv][d] 128B rows, swz (row&7)<<4
  __shared__ unsigned short Vlds[3][DH * KVB];   // [d][kv] 64B rows, swz ((row>>1)&3)<<4
  __shared__ __align__(16) float msk[3][KVB];
  __shared__ __align__(16) float bcs[2][32];

  const int t = threadIdx.x;
  const int lane = t & 63;
  const int wave = t >> 6;
  const int o = blockIdx.x;
  const int wg = (o & 7) * (NBLK / 8) + (o >> 3);  // bijective: 1536 % 8 == 0
  const int head = wg >> 7;                        // 128 blocks per head
  const int rem = wg & 127;
  const int qb = rem >> 1;
  const int sp = rem & 1;
  const int q0 = qb * 64 + wave * 32;
  const int kvb0 = sp * HALF;
  const int lm = lane & 31;
  const int h = lane >> 5;

  // Q B-fragments (col = q = lm, k-octet = d = 16ks + 8h .. +8)
  short8 qf[4];
#pragma unroll
  for (int ks = 0; ks < 4; ++ks)
    qf[ks] = *reinterpret_cast<const short8*>(
        Q + (size_t)(q0 + lm) * EMB + head * DH + ks * 16 + h * 8);

  f32x16 oacc[2];
#pragma unroll
  for (int n = 0; n < 2; ++n)
#pragma unroll
    for (int r = 0; r < 16; ++r) oacc[n][r] = 0.f;
  float mrun = -3.0e38f, lrun = 0.f;

  const int ksrow = t >> 3;         // 0..15
  const int kscol = (t & 7) * 16;
  const int vsrow = t >> 2;         // 0..31
  const int vscol = (t & 3) * 16;

  // 5 vmem ops per wave per STAGE: 2x K + 2x V gl_lds16 + 1x mask gl_lds4
  auto STAGE = [&](int buf, int kt2) {
    const int kv0 = kvb0 + kt2 * KVB;
#pragma unroll
    for (int i = 0; i < 2; ++i) {
      int krow = i * 16 + ksrow;
      int kcb = kscol ^ ((krow & 7) << 4);
      gl_lds16(Kb + (size_t)(kv0 + krow) * EMB + head * DH + (kcb >> 1),
               (char*)Klds + buf * 4096 + i * 2048 + t * 16);
      int vrow = i * 32 + vsrow;
      int vcb = vscol ^ (((vrow >> 1) & 3) << 4);
      gl_lds16(Vt + (size_t)(head * DH + vrow) * SEQ + kv0 + (vcb >> 1),
               (char*)Vlds + buf * 4096 + i * 2048 + t * 16);
    }
    if (lane < 32) gl_lds4(mb2 + kv0 + lane, &msk[buf][0]);
  };

  constexpr int NT = HALF / KVB;   // 64
  STAGE(0, 0);
  STAGE(1, 1);

  for (int kt = 0; kt < NT; ++kt) {
    if (kt < NT - 1) {
      asm volatile("s_waitcnt vmcnt(5)" ::: "memory");
    } else {
      asm volatile("s_waitcnt vmcnt(0)" ::: "memory");
    }
    __builtin_amdgcn_s_barrier();
    if (kt + 2 < NT) STAGE((kt + 2) % 3, kt + 2);
    const int cur = kt % 3;

    f32x4 mbv[4];
#pragma unroll
    for (int a = 0; a < 4; ++a)
      mbv[a] = *reinterpret_cast<const f32x4*>(&msk[cur][a * 8 + h * 4]);

    // QK^T swapped: C[kv][q]; A = K-frag (row kv=lm, d-octet), B = Q
    f32x16 s;
#pragma unroll
    for (int r = 0; r < 16; ++r) s[r] = 0.f;
    __builtin_amdgcn_s_setprio(1);
#pragma unroll
    for (int ks = 0; ks < 4; ++ks) {
      int cb = (ks * 32 + h * 16) ^ ((lm & 7) << 4);
      short8 kf = *reinterpret_cast<const short8*>((const char*)Klds + cur * 4096 + lm * 128 + cb);
      s = __builtin_amdgcn_mfma_f32_32x32x16_bf16(kf, qf[ks], s, 0, 0, 0);
    }
    __builtin_amdgcn_s_setprio(0);

    const float sc2 = 0.125f * LOG2E;
#pragma unroll
    for (int r = 0; r < 16; ++r)
      s[r] = fmaf(s[r], sc2, mbv[r >> 2][r & 3]);

    // row max: tree over 16 lane-local values + cross-half permlane
    float red[16];
#pragma unroll
    for (int r = 0; r < 16; ++r) red[r] = s[r];
#pragma unroll
    for (int off = 8; off >= 1; off >>= 1)
#pragma unroll
      for (int r = 0; r < off; ++r) red[r] = fmaxf(red[r], red[r + off]);
    float pm = xhalf_max(red[0]);

    // defer-max
    if (!__all(pm <= mrun + 8.0f)) {
      float mnew = fmaxf(mrun, pm);
      float sf = __builtin_amdgcn_exp2f(mrun - mnew);
      mrun = mnew;
      lrun *= sf;
      bcs[wave][lm] = sf;
      f32x4 sv[4];
#pragma unroll
      for (int a = 0; a < 4; ++a)
        sv[a] = *reinterpret_cast<const f32x4*>(&bcs[wave][a * 8 + h * 4]);
#pragma unroll
      for (int n = 0; n < 2; ++n)
#pragma unroll
        for (int r = 0; r < 16; ++r)
          oacc[n][r] *= sv[r >> 2][r & 3];
    }

    // P = exp2(s - m)
#pragma unroll
    for (int r = 0; r < 16; ++r)
      s[r] = __builtin_amdgcn_exp2f(s[r] - mrun);

    // row sum
    float rs[16];
#pragma unroll
    for (int r = 0; r < 16; ++r) rs[r] = s[r];
#pragma unroll
    for (int off = 8; off >= 1; off >>= 1)
#pragma unroll
      for (int r = 0; r < off; ++r) rs[r] += rs[r + off];
    lrun += xhalf_sum(rs[0]);

    // P -> bf16 A-fragments (T12: cvt_pk + permlane32_swap)
    uint32_t r0[4], r1[4];
#pragma unroll
    for (int a = 0; a < 4; ++a) {
      asm("v_cvt_pk_bf16_f32 %0, %1, %2" : "=v"(r0[a]) : "v"(s[4 * a]), "v"(s[4 * a + 1]));
      asm("v_cvt_pk_bf16_f32 %0, %1, %2" : "=v"(r1[a]) : "v"(s[4 * a + 2]), "v"(s[4 * a + 3]));
    }
    short8 pa[2];
#pragma unroll
    for (int ksl = 0; ksl < 2; ++ksl) {
      uint32x2 w0 = __builtin_amdgcn_permlane32_swap(r0[2 * ksl], r0[2 * ksl + 1], false, false);
      uint32x2 w1 = __builtin_amdgcn_permlane32_swap(r1[2 * ksl], r1[2 * ksl + 1], false, false);
      union { short8 s8; uint32_t u[4]; } pk;
      pk.u[0] = w0[0]; pk.u[1] = w1[0]; pk.u[2] = w0[1]; pk.u[3] = w1[1];
      pa[ksl] = pk.s8;
    }

    // PV: oacc[n] += P * V
    __builtin_amdgcn_s_setprio(1);
#pragma unroll
    for (int n = 0; n < 2; ++n)
#pragma unroll
      for (int ks = 0; ks < 2; ++ks) {
        int row = n * 32 + lm;
        int cb = (ks * 32 + h * 16) ^ (((row >> 1) & 3) << 4);
        short8 vf = *reinterpret_cast<const short8*>((const char*)Vlds + cur * 4096 + row * 64 + cb);
        oacc[n] = __builtin_amdgcn_mfma_f32_32x32x16_bf16(pa[ks], vf, oacc[n], 0, 0, 0);
      }
    __builtin_amdgcn_s_setprio(0);
  }

  // epilogue: partial store (unnormalized O + m + l)
  float* ob = opart + ((size_t)wg * 64 + wave * 32) * 64;
#pragma unroll
  for (int n = 0; n < 2; ++n)
#pragma unroll
    for (int r = 0; r < 16; ++r) {
      int crow = (r & 3) + 8 * (r >> 2) + 4 * h;
      ob[crow * 64 + n * 32 + lm] = oacc[n][r];
    }
  if (h == 0) {
    mpart[wg * 64 + wave * 32 + lm] = mrun;
    lpart[wg * 64 + wave * 32 + lm] = lrun;
  }
}

// ---------- merge the two KV-halves ----------
__global__ void merge_kernel(const float* __restrict__ opart,
                             const float* __restrict__ mpart,
                             const float* __restrict__ lpart,
                             unsigned short* __restrict__ Ab) {
  int tid = blockIdx.x * 256 + threadIdx.x;   // 786432 total
  int dv = tid & 15;
  int rq = tid >> 4;
  int head = rq >> 12;
  int q = rq & 4095;
  int qb = q >> 6, ql = q & 63;
  int base = (head * 128 + qb * 2) * 64 + ql;
  float m0 = mpart[base], m1 = mpart[base + 64];
  float l0 = lpart[base], l1 = lpart[base + 64];
  float m = fmaxf(m0, m1);
  float w0 = __builtin_amdgcn_exp2f(m0 - m);
  float w1 = __builtin_amdgcn_exp2f(m1 - m);
  float rl = 1.0f / fmaf(w0, l0, w1 * l1);
  f32x4 o0 = *reinterpret_cast<const f32x4*>(opart + (size_t)base * 64 + dv * 4);
  f32x4 o1 = *reinterpret_cast<const f32x4*>(opart + (size_t)(base + 64) * 64 + dv * 4);
  ushort4 r;
  r.x = f2bf((o0[0] * w0 + o1[0] * w1) * rl);
  r.y = f2bf((o0[1] * w0 + o1[1] * w1) * rl);
  r.z = f2bf((o0[2] * w0 + o1[2] * w1) * rl);
  r.w = f2bf((o0[3] * w0 + o1[3] * w1) * rl);
  *reinterpret_cast<ushort4*>(Ab + (size_t)q * EMB + head * DH + dv * 4) = r;
}

// ---------- launch ----------
extern "C" void kernel_launch(void* const* d_in, const int* in_sizes, int n_in,
                              void* d_out, int out_size, void* d_ws, size_t ws_size,
                              hipStream_t stream) {
  const float* x    = (const float*)d_in[0];
  const float* mask = (const float*)d_in[1];
  const float* Wq   = (const float*)d_in[2];
  const float* bq   = (const float*)d_in[3];
  const float* Wk   = (const float*)d_in[4];
  const float* bk   = (const float*)d_in[5];
  const float* Wv   = (const float*)d_in[6];
  const float* bv   = (const float*)d_in[7];
  const float* Wo   = (const float*)d_in[8];
  const float* bo   = (const float*)d_in[9];
  float* out = (float*)d_out;

  char* ws = (char*)d_ws;
  const size_t SZ_X = (size_t)SEQ * EMB * 2;
  const size_t SZ_W = (size_t)EMB * EMB * 2;
  unsigned short* xb  = (unsigned short*)(ws);
  unsigned short* wqb = (unsigned short*)(ws + SZ_X);
  unsigned short* wkb = (unsigned short*)(ws + SZ_X + SZ_W);
  unsigned short* wvb = (unsigned short*)(ws + SZ_X + 2 * SZ_W);
  unsigned short* wob = (unsigned short*)(ws + SZ_X + 3 * SZ_W);
  unsigned short* Qb  = (unsigned short*)(ws + SZ_X + 4 * SZ_W);
  unsigned short* Kbuf= (unsigned short*)(ws + 2 * SZ_X + 4 * SZ_W);
  unsigned short* Vb  = (unsigned short*)(ws + 3 * SZ_X + 4 * SZ_W);
  unsigned short* Vtb = (unsigned short*)(ws + 4 * SZ_X + 4 * SZ_W);
  unsigned short* Ab  = (unsigned short*)(ws + 5 * SZ_X + 4 * SZ_W);
  size_t off = 6 * SZ_X + 4 * SZ_W;
  float* mb2   = (float*)(ws + off);              off += (size_t)SEQ * 4;
  float* opart = (float*)(ws + off);              off += (size_t)NBLK * 64 * 64 * 4;
  float* mpart = (float*)(ws + off);              off += (size_t)NBLK * 64 * 4;
  float* lpart = (float*)(ws + off);

  cvt_kernel<<<1536, 256, 0, stream>>>(x, xb, SEQ * EMB);
  cvt4_kernel<<<dim3(288, 4), 256, 0, stream>>>(Wq, Wk, Wv, Wo, wqb, wkb, wvb, wob, EMB * EMB);
  mbias_kernel<<<16, 256, 0, stream>>>(mask, mb2, SEQ);

  qkv_gemm<<<dim3(SEQ / 128, EMB / 128, 3), 256, 0, stream>>>(
      xb, wqb, wkb, wvb, bq, bk, bv, Qb, Kbuf, Vb);

  transpose_kernel<<<dim3(EMB / 32, SEQ / 32), dim3(32, 8), 0, stream>>>(Vb, Vtb);

  attn_kernel<<<NBLK, 128, 0, stream>>>(Qb, Kbuf, Vtb, mb2, opart, mpart, lpart);
  merge_kernel<<<3072, 256, 0, stream>>>(opart, mpart, lpart, Ab);

  gemm_wo<<<dim3(SEQ / 128, EMB / 128), 256, 0, stream>>>(Ab, wob, bo, out);
}

// Round 8
// 136.759 us; speedup vs baseline: 1.8829x; 1.0630x over previous
//
#include <hip/hip_runtime.h>
#include <stdint.h>
#include <stddef.h>

#define EMB 768
#define SEQ 4096
#define NH 12
#define DH 64
#define LOG2E 1.44269504f
#define HALF (SEQ / 2)
#define NBLK (NH * 32 * 2)   // 768 attn blocks: 12 heads x 32 q-tiles(128) x 2 halves

typedef __attribute__((ext_vector_type(8))) short short8;
typedef __attribute__((ext_vector_type(4))) float f32x4;
typedef __attribute__((ext_vector_type(16))) float f32x16;
typedef __attribute__((ext_vector_type(2))) unsigned int uint32x2;

// ---------- helpers ----------
static __device__ __forceinline__ unsigned short f2bf(float f) {
  union { float f; uint32_t u; } v; v.f = f;
  uint32_t u = v.u;
  return (unsigned short)((u + 0x7FFFu + ((u >> 16) & 1u)) >> 16);
}

static __device__ __forceinline__ void gl_lds16(const void* g, void* l) {
  __builtin_amdgcn_global_load_lds(
      (const __attribute__((address_space(1))) uint32_t*)g,
      (__attribute__((address_space(3))) uint32_t*)l, 16, 0, 0);
}
static __device__ __forceinline__ void gl_lds4(const void* g, void* l) {
  __builtin_amdgcn_global_load_lds(
      (const __attribute__((address_space(1))) uint32_t*)g,
      (__attribute__((address_space(3))) uint32_t*)l, 4, 0, 0);
}

// cross-half combine via the permlane32_swap BUILTIN (asm with duplicated
// "+v" operands coalesces registers -> degenerate swap; round-4 failure).
static __device__ __forceinline__ float xhalf_max(float v) {
  union { float f; unsigned int u; } x; x.f = v;
  uint32x2 r = __builtin_amdgcn_permlane32_swap(x.u, x.u, false, false);
  union { unsigned int u; float f; } a, b; a.u = r[0]; b.u = r[1];
  return fmaxf(a.f, b.f);
}
static __device__ __forceinline__ float xhalf_sum(float v) {
  union { float f; unsigned int u; } x; x.f = v;
  uint32x2 r = __builtin_amdgcn_permlane32_swap(x.u, x.u, false, false);
  union { unsigned int u; float f; } a, b; a.u = r[0]; b.u = r[1];
  return a.f + b.f;
}

// ---------- fp32 -> bf16 convert ----------
__global__ void cvt_kernel(const float* __restrict__ in,
                           unsigned short* __restrict__ out, int n) {
  int stride = gridDim.x * blockDim.x * 4;
  for (int i = (blockIdx.x * blockDim.x + threadIdx.x) * 4; i < n; i += stride) {
    float4 v = *reinterpret_cast<const float4*>(in + i);
    ushort4 o;
    o.x = f2bf(v.x); o.y = f2bf(v.y); o.z = f2bf(v.z); o.w = f2bf(v.w);
    *reinterpret_cast<ushort4*>(out + i) = o;
  }
}

__global__ void cvt4_kernel(const float* __restrict__ i0, const float* __restrict__ i1,
                            const float* __restrict__ i2, const float* __restrict__ i3,
                            unsigned short* __restrict__ o0, unsigned short* __restrict__ o1,
                            unsigned short* __restrict__ o2, unsigned short* __restrict__ o3,
                            int n) {
  int y = blockIdx.y;
  const float* in = y == 0 ? i0 : y == 1 ? i1 : y == 2 ? i2 : i3;
  unsigned short* out = y == 0 ? o0 : y == 1 ? o1 : y == 2 ? o2 : o3;
  int stride = gridDim.x * blockDim.x * 4;
  for (int i = (blockIdx.x * blockDim.x + threadIdx.x) * 4; i < n; i += stride) {
    float4 v = *reinterpret_cast<const float4*>(in + i);
    ushort4 o;
    o.x = f2bf(v.x); o.y = f2bf(v.y); o.z = f2bf(v.z); o.w = f2bf(v.w);
    *reinterpret_cast<ushort4*>(out + i) = o;
  }
}

// mask -> additive bias in exp2 domain
__global__ void mbias_kernel(const float* __restrict__ mask, float* __restrict__ mb2, int n) {
  int i = blockIdx.x * blockDim.x + threadIdx.x;
  if (i < n) mb2[i] = -10000.f * (1.f - mask[i]) * LOG2E;
}

// ---------- GEMM core: C[M][N] = A[M][K] * W[N][K]^T + bias ----------
template <int OUT_F32>
static __device__ __forceinline__ void gemm128(
    const unsigned short* __restrict__ A, const unsigned short* __restrict__ W,
    const float* __restrict__ bias, void* __restrict__ Cout,
    int M, int N, int K, int bm, int bn) {
  __shared__ unsigned short Alds[128 * 64];
  __shared__ unsigned short Blds[128 * 64];
  const int t = threadIdx.x;
  const int lane = t & 63;
  const int wave = t >> 6;
  const int wr = wave >> 1, wc = wave & 1;
  const int lm = lane & 15, lg = lane >> 4;

  f32x4 acc[4][4];
#pragma unroll
  for (int i = 0; i < 4; ++i)
#pragma unroll
    for (int j = 0; j < 4; ++j) acc[i][j] = (f32x4){0.f, 0.f, 0.f, 0.f};

  const int srow = t >> 3;
  const int scsw = (t & 7) * 16;

  const int nK = K >> 6;
  for (int kt = 0; kt < nK; ++kt) {
    const int k0 = kt << 6;
#pragma unroll
    for (int i = 0; i < 4; ++i) {
      int row = i * 32 + srow;
      int cb = scsw ^ ((row & 7) << 4);
      gl_lds16(A + (size_t)(bm * 128 + row) * K + k0 + (cb >> 1),
               (char*)Alds + i * 4096 + t * 16);
      gl_lds16(W + (size_t)(bn * 128 + row) * K + k0 + (cb >> 1),
               (char*)Blds + i * 4096 + t * 16);
    }
    __syncthreads();
#pragma unroll
    for (int kk = 0; kk < 2; ++kk) {
      short8 af[4], bfr[4];
#pragma unroll
      for (int i = 0; i < 4; ++i) {
        int rowa = wr * 64 + i * 16 + lm;
        int cba = (kk * 64 + lg * 16) ^ ((rowa & 7) << 4);
        af[i] = *reinterpret_cast<const short8*>((const char*)Alds + rowa * 128 + cba);
        int rowb = wc * 64 + i * 16 + lm;
        int cbb = (kk * 64 + lg * 16) ^ ((rowb & 7) << 4);
        bfr[i] = *reinterpret_cast<const short8*>((const char*)Blds + rowb * 128 + cbb);
      }
#pragma unroll
      for (int i = 0; i < 4; ++i)
#pragma unroll
        for (int j = 0; j < 4; ++j)
          acc[i][j] = __builtin_amdgcn_mfma_f32_16x16x32_bf16(af[i], bfr[j], acc[i][j], 0, 0, 0);
    }
    __syncthreads();
  }
#pragma unroll
  for (int i = 0; i < 4; ++i) {
    int row0 = bm * 128 + wr * 64 + i * 16 + lg * 4;
#pragma unroll
    for (int j = 0; j < 4; ++j) {
      int col = bn * 128 + wc * 64 + j * 16 + lm;
      float b = bias[col];
#pragma unroll
      for (int r = 0; r < 4; ++r) {
        float v = acc[i][j][r] + b;
        if (OUT_F32)
          ((float*)Cout)[(size_t)(row0 + r) * N + col] = v;
        else
          ((unsigned short*)Cout)[(size_t)(row0 + r) * N + col] = f2bf(v);
      }
    }
  }
}

__global__ __launch_bounds__(256, 2) void gemm_wo(
    const unsigned short* __restrict__ A, const unsigned short* __restrict__ W,
    const float* __restrict__ bias, float* __restrict__ C) {
  gemm128<1>(A, W, bias, C, SEQ, EMB, EMB, blockIdx.x, blockIdx.y);
}

__global__ __launch_bounds__(256, 2) void qkv_gemm(
    const unsigned short* __restrict__ A,
    const unsigned short* __restrict__ W0, const unsigned short* __restrict__ W1,
    const unsigned short* __restrict__ W2,
    const float* __restrict__ b0, const float* __restrict__ b1, const float* __restrict__ b2,
    unsigned short* __restrict__ O0, unsigned short* __restrict__ O1,
    unsigned short* __restrict__ O2) {
  const int z = blockIdx.z;
  const unsigned short* W = z == 0 ? W0 : z == 1 ? W1 : W2;
  const float* bias = z == 0 ? b0 : z == 1 ? b1 : b2;
  unsigned short* O = z == 0 ? O0 : z == 1 ? O1 : O2;
  gemm128<0>(A, W, bias, O, SEQ, EMB, EMB, blockIdx.x, blockIdx.y);
}

// ---------- V transpose: V[SEQ][EMB] -> Vt[EMB][SEQ] (bf16) ----------
__global__ void transpose_kernel(const unsigned short* __restrict__ in,
                                 unsigned short* __restrict__ out) {
  __shared__ unsigned short tile[32][33];
  int tx = threadIdx.x, ty = threadIdx.y;   // 32 x 8
  int e0 = blockIdx.x * 32, s0 = blockIdx.y * 32;
#pragma unroll
  for (int i = 0; i < 4; ++i)
    tile[ty + i * 8][tx] = in[(size_t)(s0 + ty + i * 8) * EMB + e0 + tx];
  __syncthreads();
#pragma unroll
  for (int i = 0; i < 4; ++i)
    out[(size_t)(e0 + ty + i * 8) * SEQ + s0 + tx] = tile[tx][ty + i * 8];
}

// ---------- flash attention: split-2, 4-wave blocks, KVB=64, dbuf ----------
// grid: 768 blocks = 12 heads x 32 q-tiles(128 rows) x 2 kv-halves.
// 768 = 3 blocks/CU EXACTLY (no ragged dispatch tail); 4 waves/block ->
// 12 waves/CU. LDS 33.3KB (dbuf). T3 minimum-2-phase: STAGE(next);
// compute(cur); __syncthreads(). Barrier drain is free: loads are ~1500cy
// old by then. Partial (O,m,l) out; merge_kernel combines halves.
__global__ __launch_bounds__(256, 3) void attn_kernel(
    const unsigned short* __restrict__ Q, const unsigned short* __restrict__ Kb,
    const unsigned short* __restrict__ Vt, const float* __restrict__ mb2,
    float* __restrict__ opart, float* __restrict__ mpart,
    float* __restrict__ lpart) {
  __shared__ unsigned short Klds[2][64 * DH];   // [kv][d] 128B rows, swz (row&7)<<4
  __shared__ unsigned short Vlds[2][DH * 64];   // [d][kv] 128B rows, swz (row&7)<<4
  __shared__ __align__(16) float msk[2][64];
  __shared__ __align__(16) float bcs[4][32];

  const int t = threadIdx.x;
  const int lane = t & 63;
  const int wave = t >> 6;
  const int o = blockIdx.x;
  const int wg = (o & 7) * (NBLK / 8) + (o >> 3);  // bijective: 768 % 8 == 0
  const int head = wg >> 6;                        // 64 blocks per head
  const int rem = wg & 63;
  const int qb = rem >> 1;                         // q-tile of 128 rows
  const int sp = rem & 1;
  const int q0 = qb * 128 + wave * 32;
  const int kvb0 = sp * HALF;
  const int lm = lane & 31;
  const int h = lane >> 5;

  // Q B-fragments (col = q = lm, k-octet = d = 16ks + 8h .. +8)
  short8 qf[4];
#pragma unroll
  for (int ks = 0; ks < 4; ++ks)
    qf[ks] = *reinterpret_cast<const short8*>(
        Q + (size_t)(q0 + lm) * EMB + head * DH + ks * 16 + h * 8);

  f32x16 oacc[2];
#pragma unroll
  for (int n = 0; n < 2; ++n)
#pragma unroll
    for (int r = 0; r < 16; ++r) oacc[n][r] = 0.f;
  float mrun = -3.0e38f, lrun = 0.f;

  const int srow = t >> 3;          // 0..31
  const int scol = (t & 7) * 16;    // byte col

  // 5 vmem ops per wave per STAGE: 2x K + 2x V gl_lds16 + 1x mask gl_lds4
  auto STAGE = [&](int buf, int kt2) {
    const int kv0 = kvb0 + kt2 * 64;
#pragma unroll
    for (int i = 0; i < 2; ++i) {
      int row = i * 32 + srow;
      int cb = scol ^ ((row & 7) << 4);
      gl_lds16(Kb + (size_t)(kv0 + row) * EMB + head * DH + (cb >> 1),
               (char*)Klds + buf * 8192 + i * 4096 + t * 16);
      gl_lds16(Vt + (size_t)(head * DH + row) * SEQ + kv0 + (cb >> 1),
               (char*)Vlds + buf * 8192 + i * 4096 + t * 16);
    }
    gl_lds4(mb2 + kv0 + lane, &msk[buf][0]);   // all 4 waves dup: benign
  };

  constexpr int NT = HALF / 64;   // 32
  STAGE(0, 0);
  __syncthreads();

  for (int kt = 0; kt < NT; ++kt) {
    const int buf = kt & 1;
    if (kt + 1 < NT) STAGE(buf ^ 1, kt + 1);

    // mask bias
    f32x4 mbv[2][4];
#pragma unroll
    for (int tt = 0; tt < 2; ++tt)
#pragma unroll
      for (int a = 0; a < 4; ++a)
        mbv[tt][a] = *reinterpret_cast<const f32x4*>(&msk[buf][tt * 32 + a * 8 + h * 4]);

    // QK^T swapped: C[kv][q]; A = K-frag (row kv, d-octet), B = Q
    f32x16 s[2];
    __builtin_amdgcn_s_setprio(1);
#pragma unroll
    for (int tt = 0; tt < 2; ++tt) {
#pragma unroll
      for (int r = 0; r < 16; ++r) s[tt][r] = 0.f;
#pragma unroll
      for (int ks = 0; ks < 4; ++ks) {
        int row = tt * 32 + lm;
        int cb = (ks * 32 + h * 16) ^ ((row & 7) << 4);
        short8 kf = *reinterpret_cast<const short8*>(
            (const char*)Klds + buf * 8192 + row * 128 + cb);
        s[tt] = __builtin_amdgcn_mfma_f32_32x32x16_bf16(kf, qf[ks], s[tt], 0, 0, 0);
      }
    }
    __builtin_amdgcn_s_setprio(0);

    // scale (exp2 domain) + mask bias
    const float sc2 = 0.125f * LOG2E;
#pragma unroll
    for (int tt = 0; tt < 2; ++tt)
#pragma unroll
      for (int r = 0; r < 16; ++r)
        s[tt][r] = fmaf(s[tt][r], sc2, mbv[tt][r >> 2][r & 3]);

    // row max: tree over 32 lane-local values + 1 cross-half permlane swap
    float red[8];
#pragma unroll
    for (int r = 0; r < 8; ++r)
      red[r] = fmaxf(fmaxf(s[0][r], s[0][r + 8]), fmaxf(s[1][r], s[1][r + 8]));
#pragma unroll
    for (int off = 4; off >= 1; off >>= 1)
#pragma unroll
      for (int r = 0; r < off; ++r) red[r] = fmaxf(red[r], red[r + off]);
    float pm = xhalf_max(red[0]);

    // defer-max: rescale O only when max grows past threshold
    if (!__all(pm <= mrun + 8.0f)) {
      float mnew = fmaxf(mrun, pm);
      float sf = __builtin_amdgcn_exp2f(mrun - mnew);
      mrun = mnew;
      lrun *= sf;
      bcs[wave][lm] = sf;
      f32x4 sv[4];
#pragma unroll
      for (int a = 0; a < 4; ++a)
        sv[a] = *reinterpret_cast<const f32x4*>(&bcs[wave][a * 8 + h * 4]);
#pragma unroll
      for (int n = 0; n < 2; ++n)
#pragma unroll
        for (int r = 0; r < 16; ++r)
          oacc[n][r] *= sv[r >> 2][r & 3];
    }

    // P = exp2(s - m)
#pragma unroll
    for (int tt = 0; tt < 2; ++tt)
#pragma unroll
      for (int r = 0; r < 16; ++r)
        s[tt][r] = __builtin_amdgcn_exp2f(s[tt][r] - mrun);

    // row sum: tree + cross-half
    float rs[8];
#pragma unroll
    for (int r = 0; r < 8; ++r)
      rs[r] = (s[0][r] + s[0][r + 8]) + (s[1][r] + s[1][r + 8]);
#pragma unroll
    for (int off = 4; off >= 1; off >>= 1)
#pragma unroll
      for (int r = 0; r < off; ++r) rs[r] += rs[r + off];
    lrun += xhalf_sum(rs[0]);

    // P -> bf16 A-fragments (T12: cvt_pk + permlane32_swap)
    short8 pa[4];
#pragma unroll
    for (int tt = 0; tt < 2; ++tt) {
      uint32_t r0[4], r1[4];
#pragma unroll
      for (int a = 0; a < 4; ++a) {
        asm("v_cvt_pk_bf16_f32 %0, %1, %2" : "=v"(r0[a]) : "v"(s[tt][4 * a]), "v"(s[tt][4 * a + 1]));
        asm("v_cvt_pk_bf16_f32 %0, %1, %2" : "=v"(r1[a]) : "v"(s[tt][4 * a + 2]), "v"(s[tt][4 * a + 3]));
      }
#pragma unroll
      for (int ksl = 0; ksl < 2; ++ksl) {
        uint32x2 w0 = __builtin_amdgcn_permlane32_swap(r0[2 * ksl], r0[2 * ksl + 1], false, false);
        uint32x2 w1 = __builtin_amdgcn_permlane32_swap(r1[2 * ksl], r1[2 * ksl + 1], false, false);
        union { short8 s8; uint32_t u[4]; } pk;
        pk.u[0] = w0[0]; pk.u[1] = w1[0]; pk.u[2] = w0[1]; pk.u[3] = w1[1];
        pa[tt * 2 + ksl] = pk.s8;
      }
    }

    // PV: oacc[n] += P * V
    __builtin_amdgcn_s_setprio(1);
#pragma unroll
    for (int n = 0; n < 2; ++n)
#pragma unroll
      for (int ks = 0; ks < 4; ++ks) {
        int row = n * 32 + lm;
        int cb = (ks * 32 + h * 16) ^ ((row & 7) << 4);
        short8 vf = *reinterpret_cast<const short8*>(
            (const char*)Vlds + buf * 8192 + row * 128 + cb);
        oacc[n] = __builtin_amdgcn_mfma_f32_32x32x16_bf16(pa[ks], vf, oacc[n], 0, 0, 0);
      }
    __builtin_amdgcn_s_setprio(0);

    __syncthreads();
  }

  // epilogue: partial store (unnormalized O + m + l)
  float* ob = opart + ((size_t)(sp * NH + head) * SEQ + q0) * 64;
#pragma unroll
  for (int n = 0; n < 2; ++n)
#pragma unroll
    for (int r = 0; r < 16; ++r) {
      int crow = (r & 3) + 8 * (r >> 2) + 4 * h;
      ob[crow * 64 + n * 32 + lm] = oacc[n][r];
    }
  if (h == 0) {
    mpart[(size_t)(sp * NH + head) * SEQ + q0 + lm] = mrun;
    lpart[(size_t)(sp * NH + head) * SEQ + q0 + lm] = lrun;
  }
}

// ---------- merge the two KV-halves ----------
__global__ void merge_kernel(const float* __restrict__ opart,
                             const float* __restrict__ mpart,
                             const float* __restrict__ lpart,
                             unsigned short* __restrict__ Ab) {
  int tid = blockIdx.x * 256 + threadIdx.x;   // 786432 total
  int dv = tid & 15;
  int rq = tid >> 4;
  int head = rq >> 12;
  int q = rq & 4095;
  size_t i0 = (size_t)head * SEQ + q;
  size_t i1 = (size_t)(NH + head) * SEQ + q;
  float m0 = mpart[i0], m1 = mpart[i1];
  float l0 = lpart[i0], l1 = lpart[i1];
  float m = fmaxf(m0, m1);
  float w0 = __builtin_amdgcn_exp2f(m0 - m);
  float w1 = __builtin_amdgcn_exp2f(m1 - m);
  float rl = 1.0f / fmaf(w0, l0, w1 * l1);
  f32x4 o0 = *reinterpret_cast<const f32x4*>(opart + i0 * 64 + dv * 4);
  f32x4 o1 = *reinterpret_cast<const f32x4*>(opart + i1 * 64 + dv * 4);
  ushort4 r;
  r.x = f2bf((o0[0] * w0 + o1[0] * w1) * rl);
  r.y = f2bf((o0[1] * w0 + o1[1] * w1) * rl);
  r.z = f2bf((o0[2] * w0 + o1[2] * w1) * rl);
  r.w = f2bf((o0[3] * w0 + o1[3] * w1) * rl);
  *reinterpret_cast<ushort4*>(Ab + (size_t)q * EMB + head * DH + dv * 4) = r;
}

// ---------- launch ----------
extern "C" void kernel_launch(void* const* d_in, const int* in_sizes, int n_in,
                              void* d_out, int out_size, void* d_ws, size_t ws_size,
                              hipStream_t stream) {
  const float* x    = (const float*)d_in[0];
  const float* mask = (const float*)d_in[1];
  const float* Wq   = (const float*)d_in[2];
  const float* bq   = (const float*)d_in[3];
  const float* Wk   = (const float*)d_in[4];
  const float* bk   = (const float*)d_in[5];
  const float* Wv   = (const float*)d_in[6];
  const float* bv   = (const float*)d_in[7];
  const float* Wo   = (const float*)d_in[8];
  const float* bo   = (const float*)d_in[9];
  float* out = (float*)d_out;

  char* ws = (char*)d_ws;
  const size_t SZ_X = (size_t)SEQ * EMB * 2;
  const size_t SZ_W = (size_t)EMB * EMB * 2;
  unsigned short* xb  = (unsigned short*)(ws);
  unsigned short* wqb = (unsigned short*)(ws + SZ_X);
  unsigned short* wkb = (unsigned short*)(ws + SZ_X + SZ_W);
  unsigned short* wvb = (unsigned short*)(ws + SZ_X + 2 * SZ_W);
  unsigned short* wob = (unsigned short*)(ws + SZ_X + 3 * SZ_W);
  unsigned short* Qb  = (unsigned short*)(ws + SZ_X + 4 * SZ_W);
  unsigned short* Kbuf= (unsigned short*)(ws + 2 * SZ_X + 4 * SZ_W);
  unsigned short* Vb  = (unsigned short*)(ws + 3 * SZ_X + 4 * SZ_W);
  unsigned short* Vtb = (unsigned short*)(ws + 4 * SZ_X + 4 * SZ_W);
  unsigned short* Ab  = (unsigned short*)(ws + 5 * SZ_X + 4 * SZ_W);
  size_t off = 6 * SZ_X + 4 * SZ_W;
  float* mb2   = (float*)(ws + off);              off += (size_t)SEQ * 4;
  float* opart = (float*)(ws + off);              off += (size_t)2 * NH * SEQ * 64 * 4;
  float* mpart = (float*)(ws + off);              off += (size_t)2 * NH * SEQ * 4;
  float* lpart = (float*)(ws + off);

  cvt_kernel<<<1536, 256, 0, stream>>>(x, xb, SEQ * EMB);
  cvt4_kernel<<<dim3(288, 4), 256, 0, stream>>>(Wq, Wk, Wv, Wo, wqb, wkb, wvb, wob, EMB * EMB);
  mbias_kernel<<<16, 256, 0, stream>>>(mask, mb2, SEQ);

  qkv_gemm<<<dim3(SEQ / 128, EMB / 128, 3), 256, 0, stream>>>(
      xb, wqb, wkb, wvb, bq, bk, bv, Qb, Kbuf, Vb);

  transpose_kernel<<<dim3(EMB / 32, SEQ / 32), dim3(32, 8), 0, stream>>>(Vb, Vtb);

  attn_kernel<<<NBLK, 256, 0, stream>>>(Qb, Kbuf, Vtb, mb2, opart, mpart, lpart);
  merge_kernel<<<3072, 256, 0, stream>>>(opart, mpart, lpart, Ab);

  gemm_wo<<<dim3(SEQ / 128, EMB / 128), 256, 0, stream>>>(Ab, wob, bo, out);
}

// Round 9
// 132.021 us; speedup vs baseline: 1.9505x; 1.0359x over previous
//
#include <hip/hip_runtime.h>
#include <stdint.h>
#include <stddef.h>

#define EMB 768
#define SEQ 4096
#define NH 12
#define DH 64
#define LOG2E 1.44269504f
#define HALF (SEQ / 2)
#define NBLK (NH * 32 * 2)   // 768 attn blocks: 12 heads x 32 q-tiles(128) x 2 halves

typedef __attribute__((ext_vector_type(8))) short short8;
typedef __attribute__((ext_vector_type(2))) float f32x2;
typedef __attribute__((ext_vector_type(4))) float f32x4;
typedef __attribute__((ext_vector_type(8))) float f32x8;
typedef __attribute__((ext_vector_type(16))) float f32x16;
typedef __attribute__((ext_vector_type(2))) unsigned int uint32x2;

// ---------- helpers ----------
static __device__ __forceinline__ unsigned short f2bf(float f) {
  union { float f; uint32_t u; } v; v.f = f;
  uint32_t u = v.u;
  return (unsigned short)((u + 0x7FFFu + ((u >> 16) & 1u)) >> 16);
}

static __device__ __forceinline__ void gl_lds16(const void* g, void* l) {
  __builtin_amdgcn_global_load_lds(
      (const __attribute__((address_space(1))) uint32_t*)g,
      (__attribute__((address_space(3))) uint32_t*)l, 16, 0, 0);
}
static __device__ __forceinline__ void gl_lds4(const void* g, void* l) {
  __builtin_amdgcn_global_load_lds(
      (const __attribute__((address_space(1))) uint32_t*)g,
      (__attribute__((address_space(3))) uint32_t*)l, 4, 0, 0);
}

// cross-half combine via the permlane32_swap BUILTIN (asm with duplicated
// "+v" operands coalesces registers -> degenerate swap; round-4 failure).
static __device__ __forceinline__ float xhalf_max(float v) {
  union { float f; unsigned int u; } x; x.f = v;
  uint32x2 r = __builtin_amdgcn_permlane32_swap(x.u, x.u, false, false);
  union { unsigned int u; float f; } a, b; a.u = r[0]; b.u = r[1];
  return fmaxf(a.f, b.f);
}
static __device__ __forceinline__ float xhalf_sum(float v) {
  union { float f; unsigned int u; } x; x.f = v;
  uint32x2 r = __builtin_amdgcn_permlane32_swap(x.u, x.u, false, false);
  union { unsigned int u; float f; } a, b; a.u = r[0]; b.u = r[1];
  return a.f + b.f;
}

// vector halving helpers (static shuffles -> stays in registers)
static __device__ __forceinline__ f32x8 lo8(f32x16 v) {
  return __builtin_shufflevector(v, v, 0, 1, 2, 3, 4, 5, 6, 7);
}
static __device__ __forceinline__ f32x8 hi8(f32x16 v) {
  return __builtin_shufflevector(v, v, 8, 9, 10, 11, 12, 13, 14, 15);
}
static __device__ __forceinline__ f32x4 lo4(f32x8 v) {
  return __builtin_shufflevector(v, v, 0, 1, 2, 3);
}
static __device__ __forceinline__ f32x4 hi4(f32x8 v) {
  return __builtin_shufflevector(v, v, 4, 5, 6, 7);
}
static __device__ __forceinline__ f32x2 lo2(f32x4 v) {
  return __builtin_shufflevector(v, v, 0, 1);
}
static __device__ __forceinline__ f32x2 hi2(f32x4 v) {
  return __builtin_shufflevector(v, v, 2, 3);
}

// ---------- fused prep: fp32->bf16 of x + 4 weights, and mask bias ----------
// mb2 = -80000 * (1 - mask)  ==  (exp2-domain additive bias) / sc2, so the
// attn kernel can C-init the QK accumulator with it and scale once at the end.
__global__ void prep_kernel(const float* __restrict__ x, const float* __restrict__ mask,
                            const float* __restrict__ Wq, const float* __restrict__ Wk,
                            const float* __restrict__ Wv, const float* __restrict__ Wo,
                            unsigned short* __restrict__ xb, unsigned short* __restrict__ wqb,
                            unsigned short* __restrict__ wkb, unsigned short* __restrict__ wvb,
                            unsigned short* __restrict__ wob, float* __restrict__ mb2) {
  const int y = blockIdx.y;
  if (y == 5) {
    int i = blockIdx.x * 256 + threadIdx.x;
    if (i < SEQ) mb2[i] = -80000.f * (1.f - mask[i]);
    return;
  }
  const float* in = y == 0 ? x : y == 1 ? Wq : y == 2 ? Wk : y == 3 ? Wv : Wo;
  unsigned short* out = y == 0 ? xb : y == 1 ? wqb : y == 2 ? wkb : y == 3 ? wvb : wob;
  const int n = (y == 0) ? SEQ * EMB : EMB * EMB;
  int stride = gridDim.x * blockDim.x * 4;
  for (int i = (blockIdx.x * blockDim.x + threadIdx.x) * 4; i < n; i += stride) {
    float4 v = *reinterpret_cast<const float4*>(in + i);
    ushort4 o;
    o.x = f2bf(v.x); o.y = f2bf(v.y); o.z = f2bf(v.z); o.w = f2bf(v.w);
    *reinterpret_cast<ushort4*>(out + i) = o;
  }
}

// ---------- GEMM core: C[M][N] = A[M][K] * W[N][K]^T + bias ----------
template <int OUT_F32>
static __device__ __forceinline__ void gemm128(
    const unsigned short* __restrict__ A, const unsigned short* __restrict__ W,
    const float* __restrict__ bias, void* __restrict__ Cout,
    int M, int N, int K, int bm, int bn) {
  __shared__ unsigned short Alds[128 * 64];
  __shared__ unsigned short Blds[128 * 64];
  const int t = threadIdx.x;
  const int lane = t & 63;
  const int wave = t >> 6;
  const int wr = wave >> 1, wc = wave & 1;
  const int lm = lane & 15, lg = lane >> 4;

  f32x4 acc[4][4];
#pragma unroll
  for (int i = 0; i < 4; ++i)
#pragma unroll
    for (int j = 0; j < 4; ++j) acc[i][j] = (f32x4){0.f, 0.f, 0.f, 0.f};

  const int srow = t >> 3;
  const int scsw = (t & 7) * 16;

  const int nK = K >> 6;
  for (int kt = 0; kt < nK; ++kt) {
    const int k0 = kt << 6;
#pragma unroll
    for (int i = 0; i < 4; ++i) {
      int row = i * 32 + srow;
      int cb = scsw ^ ((row & 7) << 4);
      gl_lds16(A + (size_t)(bm * 128 + row) * K + k0 + (cb >> 1),
               (char*)Alds + i * 4096 + t * 16);
      gl_lds16(W + (size_t)(bn * 128 + row) * K + k0 + (cb >> 1),
               (char*)Blds + i * 4096 + t * 16);
    }
    __syncthreads();
#pragma unroll
    for (int kk = 0; kk < 2; ++kk) {
      short8 af[4], bfr[4];
#pragma unroll
      for (int i = 0; i < 4; ++i) {
        int rowa = wr * 64 + i * 16 + lm;
        int cba = (kk * 64 + lg * 16) ^ ((rowa & 7) << 4);
        af[i] = *reinterpret_cast<const short8*>((const char*)Alds + rowa * 128 + cba);
        int rowb = wc * 64 + i * 16 + lm;
        int cbb = (kk * 64 + lg * 16) ^ ((rowb & 7) << 4);
        bfr[i] = *reinterpret_cast<const short8*>((const char*)Blds + rowb * 128 + cbb);
      }
#pragma unroll
      for (int i = 0; i < 4; ++i)
#pragma unroll
        for (int j = 0; j < 4; ++j)
          acc[i][j] = __builtin_amdgcn_mfma_f32_16x16x32_bf16(af[i], bfr[j], acc[i][j], 0, 0, 0);
    }
    __syncthreads();
  }
#pragma unroll
  for (int i = 0; i < 4; ++i) {
    int row0 = bm * 128 + wr * 64 + i * 16 + lg * 4;
#pragma unroll
    for (int j = 0; j < 4; ++j) {
      int col = bn * 128 + wc * 64 + j * 16 + lm;
      float b = bias[col];
#pragma unroll
      for (int r = 0; r < 4; ++r) {
        float v = acc[i][j][r] + b;
        if (OUT_F32)
          ((float*)Cout)[(size_t)(row0 + r) * N + col] = v;
        else
          ((unsigned short*)Cout)[(size_t)(row0 + r) * N + col] = f2bf(v);
      }
    }
  }
}

__global__ __launch_bounds__(256, 2) void gemm_wo(
    const unsigned short* __restrict__ A, const unsigned short* __restrict__ W,
    const float* __restrict__ bias, float* __restrict__ C) {
  gemm128<1>(A, W, bias, C, SEQ, EMB, EMB, blockIdx.x, blockIdx.y);
}

__global__ __launch_bounds__(256, 2) void qkv_gemm(
    const unsigned short* __restrict__ A,
    const unsigned short* __restrict__ W0, const unsigned short* __restrict__ W1,
    const unsigned short* __restrict__ W2,
    const float* __restrict__ b0, const float* __restrict__ b1, const float* __restrict__ b2,
    unsigned short* __restrict__ O0, unsigned short* __restrict__ O1,
    unsigned short* __restrict__ O2) {
  const int z = blockIdx.z;
  const unsigned short* W = z == 0 ? W0 : z == 1 ? W1 : W2;
  const float* bias = z == 0 ? b0 : z == 1 ? b1 : b2;
  unsigned short* O = z == 0 ? O0 : z == 1 ? O1 : O2;
  gemm128<0>(A, W, bias, O, SEQ, EMB, EMB, blockIdx.x, blockIdx.y);
}

// ---------- V transpose: V[SEQ][EMB] -> Vt[EMB][SEQ] (bf16) ----------
__global__ void transpose_kernel(const unsigned short* __restrict__ in,
                                 unsigned short* __restrict__ out) {
  __shared__ unsigned short tile[32][33];
  int tx = threadIdx.x, ty = threadIdx.y;   // 32 x 8
  int e0 = blockIdx.x * 32, s0 = blockIdx.y * 32;
#pragma unroll
  for (int i = 0; i < 4; ++i)
    tile[ty + i * 8][tx] = in[(size_t)(s0 + ty + i * 8) * EMB + e0 + tx];
  __syncthreads();
#pragma unroll
  for (int i = 0; i < 4; ++i)
    out[(size_t)(e0 + ty + i * 8) * SEQ + s0 + tx] = tile[tx][ty + i * 8];
}

// ---------- flash attention: split-2, 4-wave blocks, KVB=64, dbuf ----------
// grid: 768 blocks = 12 heads x 32 q-tiles(128 rows) x 2 kv-halves = exactly
// 3 blocks/CU. QK accumulator is C-initialized with the mask bias (pre-divided
// by sc2), eliminating the zero-init and mask-add passes; softmax arithmetic
// runs on full f32x16 vectors (clang lowers to v_pk_*_f32, halving VALU issue).
__global__ __launch_bounds__(256, 3) void attn_kernel(
    const unsigned short* __restrict__ Q, const unsigned short* __restrict__ Kb,
    const unsigned short* __restrict__ Vt, const float* __restrict__ mb2,
    float* __restrict__ opart, float* __restrict__ mpart,
    float* __restrict__ lpart) {
  __shared__ unsigned short Klds[2][64 * DH];   // [kv][d] 128B rows, swz (row&7)<<4
  __shared__ unsigned short Vlds[2][DH * 64];   // [d][kv] 128B rows, swz (row&7)<<4
  __shared__ __align__(16) float msk[2][64];
  __shared__ __align__(16) float bcs[4][32];

  const int t = threadIdx.x;
  const int lane = t & 63;
  const int wave = t >> 6;
  const int o = blockIdx.x;
  const int wg = (o & 7) * (NBLK / 8) + (o >> 3);  // bijective: 768 % 8 == 0
  const int head = wg >> 6;                        // 64 blocks per head
  const int rem = wg & 63;
  const int qb = rem >> 1;                         // q-tile of 128 rows
  const int sp = rem & 1;
  const int q0 = qb * 128 + wave * 32;
  const int kvb0 = sp * HALF;
  const int lm = lane & 31;
  const int h = lane >> 5;

  // Q B-fragments (col = q = lm, k-octet = d = 16ks + 8h .. +8)
  short8 qf[4];
#pragma unroll
  for (int ks = 0; ks < 4; ++ks)
    qf[ks] = *reinterpret_cast<const short8*>(
        Q + (size_t)(q0 + lm) * EMB + head * DH + ks * 16 + h * 8);

  f32x16 oacc[2];
#pragma unroll
  for (int n = 0; n < 2; ++n)
#pragma unroll
    for (int r = 0; r < 16; ++r) oacc[n][r] = 0.f;
  float mrun = -3.0e38f, lrun = 0.f;

  const int srow = t >> 3;          // 0..31
  const int scol = (t & 7) * 16;    // byte col

  // 5 vmem ops per wave per STAGE: 2x K + 2x V gl_lds16 + 1x mask gl_lds4
  auto STAGE = [&](int buf, int kt2) {
    const int kv0 = kvb0 + kt2 * 64;
#pragma unroll
    for (int i = 0; i < 2; ++i) {
      int row = i * 32 + srow;
      int cb = scol ^ ((row & 7) << 4);
      gl_lds16(Kb + (size_t)(kv0 + row) * EMB + head * DH + (cb >> 1),
               (char*)Klds + buf * 8192 + i * 4096 + t * 16);
      gl_lds16(Vt + (size_t)(head * DH + row) * SEQ + kv0 + (cb >> 1),
               (char*)Vlds + buf * 8192 + i * 4096 + t * 16);
    }
    gl_lds4(mb2 + kv0 + lane, &msk[buf][0]);   // all 4 waves dup: benign
  };

  constexpr int NT = HALF / 64;   // 32
  STAGE(0, 0);
  __syncthreads();

  for (int kt = 0; kt < NT; ++kt) {
    const int buf = kt & 1;
    if (kt + 1 < NT) STAGE(buf ^ 1, kt + 1);

    // QK^T swapped: C[kv][q]; ACC INIT = mask bias / sc2 (from staged LDS)
    f32x16 s[2];
#pragma unroll
    for (int tt = 0; tt < 2; ++tt)
#pragma unroll
      for (int a = 0; a < 4; ++a) {
        f32x4 m = *reinterpret_cast<const f32x4*>(&msk[buf][tt * 32 + a * 8 + h * 4]);
#pragma unroll
        for (int i = 0; i < 4; ++i) s[tt][a * 4 + i] = m[i];
      }

    __builtin_amdgcn_s_setprio(1);
#pragma unroll
    for (int tt = 0; tt < 2; ++tt)
#pragma unroll
      for (int ks = 0; ks < 4; ++ks) {
        int row = tt * 32 + lm;
        int cb = (ks * 32 + h * 16) ^ ((row & 7) << 4);
        short8 kf = *reinterpret_cast<const short8*>(
            (const char*)Klds + buf * 8192 + row * 128 + cb);
        s[tt] = __builtin_amdgcn_mfma_f32_32x32x16_bf16(kf, qf[ks], s[tt], 0, 0, 0);
      }
    __builtin_amdgcn_s_setprio(0);

    // single scale pass (mask already inside acc): s *= sc2  [pk_mul x16]
    const float sc2 = 0.125f * LOG2E;
    s[0] = s[0] * sc2;
    s[1] = s[1] * sc2;

    // row max: vector halving tree + cross-half permlane
    f32x16 mx16 = __builtin_elementwise_max(s[0], s[1]);
    f32x8 mx8 = __builtin_elementwise_max(lo8(mx16), hi8(mx16));
    f32x4 mx4 = __builtin_elementwise_max(lo4(mx8), hi4(mx8));
    f32x2 mx2 = __builtin_elementwise_max(lo2(mx4), hi2(mx4));
    float pm = xhalf_max(fmaxf(mx2[0], mx2[1]));

    // defer-max: rescale O only when max grows past threshold
    if (!__all(pm <= mrun + 8.0f)) {
      float mnew = fmaxf(mrun, pm);
      float sf = __builtin_amdgcn_exp2f(mrun - mnew);
      mrun = mnew;
      lrun *= sf;
      bcs[wave][lm] = sf;
      f32x16 svv;
#pragma unroll
      for (int a = 0; a < 4; ++a) {
        f32x4 sv = *reinterpret_cast<const f32x4*>(&bcs[wave][a * 8 + h * 4]);
#pragma unroll
        for (int i = 0; i < 4; ++i) svv[a * 4 + i] = sv[i];
      }
      oacc[0] = oacc[0] * svv;
      oacc[1] = oacc[1] * svv;
    }

    // P = exp2(s - m): vector sub [pk x16], scalar exp per component
    s[0] = s[0] - mrun;
    s[1] = s[1] - mrun;
#pragma unroll
    for (int tt = 0; tt < 2; ++tt)
#pragma unroll
      for (int r = 0; r < 16; ++r)
        s[tt][r] = __builtin_amdgcn_exp2f(s[tt][r]);

    // row sum: vector halving tree + cross-half permlane
    f32x16 sm16 = s[0] + s[1];
    f32x8 sm8 = lo8(sm16) + hi8(sm16);
    f32x4 sm4 = lo4(sm8) + hi4(sm8);
    f32x2 sm2 = lo2(sm4) + hi2(sm4);
    lrun += xhalf_sum(sm2[0] + sm2[1]);

    // P -> bf16 A-fragments (T12: cvt_pk + permlane32_swap)
    short8 pa[4];
#pragma unroll
    for (int tt = 0; tt < 2; ++tt) {
      uint32_t r0[4], r1[4];
#pragma unroll
      for (int a = 0; a < 4; ++a) {
        asm("v_cvt_pk_bf16_f32 %0, %1, %2" : "=v"(r0[a]) : "v"(s[tt][4 * a]), "v"(s[tt][4 * a + 1]));
        asm("v_cvt_pk_bf16_f32 %0, %1, %2" : "=v"(r1[a]) : "v"(s[tt][4 * a + 2]), "v"(s[tt][4 * a + 3]));
      }
#pragma unroll
      for (int ksl = 0; ksl < 2; ++ksl) {
        uint32x2 w0 = __builtin_amdgcn_permlane32_swap(r0[2 * ksl], r0[2 * ksl + 1], false, false);
        uint32x2 w1 = __builtin_amdgcn_permlane32_swap(r1[2 * ksl], r1[2 * ksl + 1], false, false);
        union { short8 s8; uint32_t u[4]; } pk;
        pk.u[0] = w0[0]; pk.u[1] = w1[0]; pk.u[2] = w0[1]; pk.u[3] = w1[1];
        pa[tt * 2 + ksl] = pk.s8;
      }
    }

    // PV: oacc[n] += P * V
    __builtin_amdgcn_s_setprio(1);
#pragma unroll
    for (int n = 0; n < 2; ++n)
#pragma unroll
      for (int ks = 0; ks < 4; ++ks) {
        int row = n * 32 + lm;
        int cb = (ks * 32 + h * 16) ^ ((row & 7) << 4);
        short8 vf = *reinterpret_cast<const short8*>(
            (const char*)Vlds + buf * 8192 + row * 128 + cb);
        oacc[n] = __builtin_amdgcn_mfma_f32_32x32x16_bf16(pa[ks], vf, oacc[n], 0, 0, 0);
      }
    __builtin_amdgcn_s_setprio(0);

    __syncthreads();
  }

  // epilogue: partial store (unnormalized O + m + l)
  float* ob = opart + ((size_t)(sp * NH + head) * SEQ + q0) * 64;
#pragma unroll
  for (int n = 0; n < 2; ++n)
#pragma unroll
    for (int r = 0; r < 16; ++r) {
      int crow = (r & 3) + 8 * (r >> 2) + 4 * h;
      ob[crow * 64 + n * 32 + lm] = oacc[n][r];
    }
  if (h == 0) {
    mpart[(size_t)(sp * NH + head) * SEQ + q0 + lm] = mrun;
    lpart[(size_t)(sp * NH + head) * SEQ + q0 + lm] = lrun;
  }
}

// ---------- merge the two KV-halves ----------
__global__ void merge_kernel(const float* __restrict__ opart,
                             const float* __restrict__ mpart,
                             const float* __restrict__ lpart,
                             unsigned short* __restrict__ Ab) {
  int tid = blockIdx.x * 256 + threadIdx.x;   // 786432 total
  int dv = tid & 15;
  int rq = tid >> 4;
  int head = rq >> 12;
  int q = rq & 4095;
  size_t i0 = (size_t)head * SEQ + q;
  size_t i1 = (size_t)(NH + head) * SEQ + q;
  float m0 = mpart[i0], m1 = mpart[i1];
  float l0 = lpart[i0], l1 = lpart[i1];
  float m = fmaxf(m0, m1);
  float w0 = __builtin_amdgcn_exp2f(m0 - m);
  float w1 = __builtin_amdgcn_exp2f(m1 - m);
  float rl = 1.0f / fmaf(w0, l0, w1 * l1);
  f32x4 o0 = *reinterpret_cast<const f32x4*>(opart + i0 * 64 + dv * 4);
  f32x4 o1 = *reinterpret_cast<const f32x4*>(opart + i1 * 64 + dv * 4);
  ushort4 r;
  r.x = f2bf((o0[0] * w0 + o1[0] * w1) * rl);
  r.y = f2bf((o0[1] * w0 + o1[1] * w1) * rl);
  r.z = f2bf((o0[2] * w0 + o1[2] * w1) * rl);
  r.w = f2bf((o0[3] * w0 + o1[3] * w1) * rl);
  *reinterpret_cast<ushort4*>(Ab + (size_t)q * EMB + head * DH + dv * 4) = r;
}

// ---------- launch ----------
extern "C" void kernel_launch(void* const* d_in, const int* in_sizes, int n_in,
                              void* d_out, int out_size, void* d_ws, size_t ws_size,
                              hipStream_t stream) {
  const float* x    = (const float*)d_in[0];
  const float* mask = (const float*)d_in[1];
  const float* Wq   = (const float*)d_in[2];
  const float* bq   = (const float*)d_in[3];
  const float* Wk   = (const float*)d_in[4];
  const float* bk   = (const float*)d_in[5];
  const float* Wv   = (const float*)d_in[6];
  const float* bv   = (const float*)d_in[7];
  const float* Wo   = (const float*)d_in[8];
  const float* bo   = (const float*)d_in[9];
  float* out = (float*)d_out;

  char* ws = (char*)d_ws;
  const size_t SZ_X = (size_t)SEQ * EMB * 2;
  const size_t SZ_W = (size_t)EMB * EMB * 2;
  unsigned short* xb  = (unsigned short*)(ws);
  unsigned short* wqb = (unsigned short*)(ws + SZ_X);
  unsigned short* wkb = (unsigned short*)(ws + SZ_X + SZ_W);
  unsigned short* wvb = (unsigned short*)(ws + SZ_X + 2 * SZ_W);
  unsigned short* wob = (unsigned short*)(ws + SZ_X + 3 * SZ_W);
  unsigned short* Qb  = (unsigned short*)(ws + SZ_X + 4 * SZ_W);
  unsigned short* Kbuf= (unsigned short*)(ws + 2 * SZ_X + 4 * SZ_W);
  unsigned short* Vb  = (unsigned short*)(ws + 3 * SZ_X + 4 * SZ_W);
  unsigned short* Vtb = (unsigned short*)(ws + 4 * SZ_X + 4 * SZ_W);
  unsigned short* Ab  = (unsigned short*)(ws + 5 * SZ_X + 4 * SZ_W);
  size_t off = 6 * SZ_X + 4 * SZ_W;
  float* mb2   = (float*)(ws + off);              off += (size_t)SEQ * 4;
  float* opart = (float*)(ws + off);              off += (size_t)2 * NH * SEQ * 64 * 4;
  float* mpart = (float*)(ws + off);              off += (size_t)2 * NH * SEQ * 4;
  float* lpart = (float*)(ws + off);

  prep_kernel<<<dim3(192, 6), 256, 0, stream>>>(
      x, mask, Wq, Wk, Wv, Wo, xb, wqb, wkb, wvb, wob, mb2);

  qkv_gemm<<<dim3(SEQ / 128, EMB / 128, 3), 256, 0, stream>>>(
      xb, wqb, wkb, wvb, bq, bk, bv, Qb, Kbuf, Vb);

  transpose_kernel<<<dim3(EMB / 32, SEQ / 32), dim3(32, 8), 0, stream>>>(Vb, Vtb);

  attn_kernel<<<NBLK, 256, 0, stream>>>(Qb, Kbuf, Vtb, mb2, opart, mpart, lpart);
  merge_kernel<<<3072, 256, 0, stream>>>(opart, mpart, lpart, Ab);

  gemm_wo<<<dim3(SEQ / 128, EMB / 128), 256, 0, stream>>>(Ab, wob, bo, out);
}